// Round 9
// baseline (707.131 us; speedup 1.0000x reference)
//
#include <hip/hip_runtime.h>
#include <stdint.h>

#define KNN_K 20
#define EPSBN 1e-5f

typedef __attribute__((ext_vector_type(4))) float f32x4;
typedef __attribute__((ext_vector_type(8))) short s16x8;
typedef __attribute__((ext_vector_type(4))) short s16x4;

__device__ __forceinline__ unsigned sortable_f32(float f) {
    unsigned u = __float_as_uint(f);
    return (u & 0x80000000u) ? ~u : (u | 0x80000000u);
}

// round-to-nearest-even float -> bf16 bit pattern
__device__ __forceinline__ short f2bf(float x) {
    unsigned u = __float_as_uint(x);
    unsigned r = (u + 0x7fffu + ((u >> 16) & 1u)) >> 16;
    return (short)r;
}
__device__ __forceinline__ float bf2f(short h) {
    return __uint_as_float(((unsigned)(unsigned short)h) << 16);
}

// ---------------- per-point squared norm ----------------
__global__ void sq_kernel(const float* __restrict__ x, float* __restrict__ sq,
                          int total, int C) {
    int i = blockIdx.x * 256 + threadIdx.x;
    if (i >= total) return;
    const float* p = x + (size_t)i * C;
    float s = 0.f;
    for (int c = 0; c < C; ++c) s += p[c] * p[c];
    sq[i] = s;
}

// ---------------- pairwise squared distances, triangular 128x128 tiles ------
// Computes only tiles bi<=bj (36 of 64) and mirror-writes the transpose.
// EXACT: fp32 add/mul are commutative bitwise; k-ascending fmaf chain is
// identical for (n,m) and (m,n).
__global__ __launch_bounds__(256) void dist128t_kernel(
    const float* __restrict__ feats, const float* __restrict__ sq,
    float* __restrict__ dist, int b0, int N, int C)
{
    int lb = blockIdx.z;
    int b = b0 + lb;
    const float* F = feats + (size_t)b * N * C;
    const float* S = sq + (size_t)b * N;
    float* D = dist + (size_t)lb * N * N;
    int t = blockIdx.x, bi = 0;
    while (t >= 8 - bi) { t -= 8 - bi; ++bi; }
    int bj = bi + t;
    int n0 = bi * 128, m0 = bj * 128;

    __shared__ float As[16][132];
    __shared__ float Bs[16][132];
    int tx = threadIdx.x & 15, ty = threadIdx.x >> 4;
    int tid = threadIdx.x;
    float acc[8][8] = {};
    for (int k0 = 0; k0 < C; k0 += 16) {
        #pragma unroll
        for (int it = 0; it < 8; ++it) {
            int idx = tid + it * 256;
            int r = idx >> 4, kk = idx & 15;
            int gk = k0 + kk;
            As[kk][r] = (gk < C) ? F[(size_t)(n0 + r) * C + gk] : 0.f;
            Bs[kk][r] = (gk < C) ? F[(size_t)(m0 + r) * C + gk] : 0.f;
        }
        __syncthreads();
        #pragma unroll
        for (int kk = 0; kk < 16; ++kk) {
            float4 a0 = *reinterpret_cast<const float4*>(&As[kk][ty * 4]);
            float4 a1 = *reinterpret_cast<const float4*>(&As[kk][64 + ty * 4]);
            float4 b0 = *reinterpret_cast<const float4*>(&Bs[kk][tx * 4]);
            float4 b1 = *reinterpret_cast<const float4*>(&Bs[kk][64 + tx * 4]);
            float av[8] = {a0.x, a0.y, a0.z, a0.w, a1.x, a1.y, a1.z, a1.w};
            float bv[8] = {b0.x, b0.y, b0.z, b0.w, b1.x, b1.y, b1.z, b1.w};
            #pragma unroll
            for (int i = 0; i < 8; ++i)
                #pragma unroll
                for (int j = 0; j < 8; ++j)
                    acc[i][j] = fmaf(av[i], bv[j], acc[i][j]);
        }
        __syncthreads();
    }
    #pragma unroll
    for (int i = 0; i < 8; ++i) {
        int n = n0 + ((i < 4) ? ty * 4 + i : 64 + ty * 4 + (i - 4));
        float sn = S[n];
        #pragma unroll
        for (int j = 0; j < 8; ++j) {
            int m = m0 + ((j < 4) ? tx * 4 + j : 64 + tx * 4 + (j - 4));
            D[(size_t)n * N + m] = (sn + S[m]) - 2.0f * acc[i][j];
        }
    }
    if (bi < bj) {
        #pragma unroll
        for (int j = 0; j < 8; ++j) {
            int m = m0 + ((j < 4) ? tx * 4 + j : 64 + tx * 4 + (j - 4));
            float sm = S[m];
            #pragma unroll
            for (int i = 0; i < 8; ++i) {
                int n = n0 + ((i < 4) ? ty * 4 + i : 64 + ty * 4 + (i - 4));
                D[(size_t)m * N + n] = (sm + S[n]) - 2.0f * acc[i][j];
            }
        }
    }
}

// ---------------- wave-per-point KNN select + aggregate + BN + ReLU ---------
// 4 points per 256-thread block, one wave each. No block barriers.
// Two-level radix select: 11-bit histogram; if the candidate set is fat
// (concentrated distances, 64-D layers) refine with the next 11 key bits.
// Both predicates are prefix-closed in key order => exact ranks.
// mode: 0 ms=val, 1 ms+=val, 2 final mean -> bf16 hi/lo split (msh/msl)
__global__ __launch_bounds__(256) void knn_agg_wave_kernel(
    const float* __restrict__ dist, const float* __restrict__ lin,
    const float* __restrict__ gam, const float* __restrict__ bet,
    const float* __restrict__ mu, const float* __restrict__ var,
    float* __restrict__ feats_out, float* __restrict__ ms,
    short* __restrict__ msh, short* __restrict__ msl,
    int b0, int N, int dil, int mode)
{
    __shared__ alignas(16) unsigned hist[4][1024];   // packed u16x2, 2048 bins
    __shared__ unsigned long long cand[4][256];
    __shared__ int nbrs[4][KNN_K];

    int tid = threadIdx.x;
    int wv = tid >> 6, lane = tid & 63;
    int p = blockIdx.x * 4 + wv;
    int lb = p / N, n = p - lb * N;
    int b = b0 + lb;
    const int R = KNN_K * dil + 1;   // smallest keys needed (incl self)

    // load 16 distances/lane (coalesced float4), build sortable keys in regs
    const float* drow = dist + ((size_t)lb * N + n) * N;
    const f32x4* drow4 = (const f32x4*)drow;
    unsigned long long k[16];
    #pragma unroll
    for (int s = 0; s < 4; ++s) {
        f32x4 v = drow4[s * 64 + lane];
        #pragma unroll
        for (int e = 0; e < 4; ++e) {
            int m = (s * 64 + lane) * 4 + e;
            k[s * 4 + e] = ((unsigned long long)sortable_f32(v[e]) << 32) | (unsigned)m;
        }
    }
    unsigned* H = hist[wv];
    uint4 z = {0u, 0u, 0u, 0u};
    #pragma unroll
    for (int i = 0; i < 4; ++i) *(uint4*)&H[lane * 16 + i * 4] = z;
    __threadfence_block();
    // level-1 histogram on top 11 bits (bin d -> word d>>1, half d&1)
    #pragma unroll
    for (int s = 0; s < 16; ++s) {
        unsigned d = (unsigned)(k[s] >> 53);
        atomicAdd(&H[d >> 1], 1u << ((d & 1) << 4));
    }
    __threadfence_block();
    // per-lane 32-bin segment count + wave inclusive scan
    unsigned w[16];
    #pragma unroll
    for (int i = 0; i < 4; ++i) *(uint4*)&w[i * 4] = *(const uint4*)&H[lane * 16 + i * 4];
    int psum = 0;
    #pragma unroll
    for (int i = 0; i < 16; ++i) psum += (int)(w[i] & 0xFFFFu) + (int)(w[i] >> 16);
    int incl = psum;
    #pragma unroll
    for (int d = 1; d < 64; d <<= 1) {
        int o = __shfl_up(incl, d, 64);
        if (lane >= d) incl += o;
    }
    int excl = incl - psum;
    int svDl = 0, c0l = 0, pl = 0;
    bool found = (excl < R && incl >= R);
    if (found) {
        int cum = excl;
        #pragma unroll
        for (int i = 0; i < 32; ++i) {
            int hv = (i & 1) ? (int)(w[i >> 1] >> 16) : (int)(w[i >> 1] & 0xFFFFu);
            if (cum + hv >= R) { svDl = lane * 32 + i; c0l = cum; pl = hv; break; }
            cum += hv;
        }
    }
    unsigned long long fm = __ballot(found);
    int src = __ffsll(fm) - 1;
    int svD  = __shfl(svDl, src, 64);
    int svC0 = __shfl(c0l, src, 64);   // count of keys with digit < svD (< R)
    int svP  = __shfl(pl, src, 64);
    int Cnt = svC0 + svP;              // count of keys with digit <= svD

    bool pred[16];
    #pragma unroll
    for (int s = 0; s < 16; ++s) pred[s] = ((unsigned)(k[s] >> 53) <= (unsigned)svD);

    if (Cnt > 96) {
        // level-2 refine within pivot bin on key bits 42..52
        #pragma unroll
        for (int i = 0; i < 4; ++i) *(uint4*)&H[lane * 16 + i * 4] = z;
        __threadfence_block();
        #pragma unroll
        for (int s = 0; s < 16; ++s) {
            if ((unsigned)(k[s] >> 53) == (unsigned)svD) {
                unsigned d2 = (unsigned)(k[s] >> 42) & 0x7FFu;
                atomicAdd(&H[d2 >> 1], 1u << ((d2 & 1) << 4));
            }
        }
        __threadfence_block();
        unsigned w2[16];
        #pragma unroll
        for (int i = 0; i < 4; ++i) *(uint4*)&w2[i * 4] = *(const uint4*)&H[lane * 16 + i * 4];
        int ps2 = 0;
        #pragma unroll
        for (int i = 0; i < 16; ++i) ps2 += (int)(w2[i] & 0xFFFFu) + (int)(w2[i] >> 16);
        int incl2 = ps2;
        #pragma unroll
        for (int d = 1; d < 64; d <<= 1) {
            int o = __shfl_up(incl2, d, 64);
            if (lane >= d) incl2 += o;
        }
        int excl2 = incl2 - ps2;
        int need = R - svC0;           // >= 1; pivot bin holds >= need keys
        int svD2l = 0, c2l = 0;
        bool f2_ = (excl2 < need && incl2 >= need);
        if (f2_) {
            int cum = excl2;
            #pragma unroll
            for (int i = 0; i < 32; ++i) {
                int hv = (i & 1) ? (int)(w2[i >> 1] >> 16) : (int)(w2[i >> 1] & 0xFFFFu);
                if (cum + hv >= need) { svD2l = lane * 32 + i; c2l = cum + hv; break; }
                cum += hv;
            }
        }
        unsigned long long fm2 = __ballot(f2_);
        int src2 = __ffsll(fm2) - 1;
        int svD2 = __shfl(svD2l, src2, 64);
        int cum2 = __shfl(c2l, src2, 64);   // in-bin count with sub <= svD2
        Cnt = svC0 + cum2;
        #pragma unroll
        for (int s = 0; s < 16; ++s) {
            unsigned d = (unsigned)(k[s] >> 53);
            pred[s] = (d < (unsigned)svD) ||
                      (d == (unsigned)svD &&
                       (((unsigned)(k[s] >> 42) & 0x7FFu) <= (unsigned)svD2));
        }
    }

    if (Cnt <= 256) {
        // ballot compaction (no atomics; order irrelevant for value-ranking)
        unsigned long long below = (1ull << lane) - 1;
        int base = 0;
        #pragma unroll
        for (int s = 0; s < 16; ++s) {
            unsigned long long mset = __ballot(pred[s]);
            if (pred[s]) {
                int pos = base + (int)__popcll(mset & below);
                cand[wv][pos] = k[s];
            }
            base += (int)__popcll(mset);
        }
        __threadfence_block();
        // owned candidates (up to 4/lane); single-pass 4-way rank
        unsigned long long my[4];
        #pragma unroll
        for (int q = 0; q < 4; ++q) {
            int slot = lane + q * 64;
            my[q] = (slot < Cnt) ? cand[wv][slot] : ~0ull;
        }
        int r0 = 0, r1 = 0, r2 = 0, r3 = 0;
        for (int c = 0; c < Cnt; ++c) {
            unsigned long long v = cand[wv][c];
            r0 += (v < my[0]) ? 1 : 0;
            r1 += (v < my[1]) ? 1 : 0;
            r2 += (v < my[2]) ? 1 : 0;
            r3 += (v < my[3]) ? 1 : 0;
        }
        int rr[4] = {r0, r1, r2, r3};
        #pragma unroll
        for (int q = 0; q < 4; ++q) {
            int slot = lane + q * 64;
            if (slot < Cnt && rr[q] >= 1) {
                int q2 = rr[q] - 1;
                if (q2 % dil == 0) {
                    int j = q2 / dil;
                    if (j < KNN_K) nbrs[wv][j] = (int)(my[q] & 0xFFFFFFFFull);
                }
            }
        }
    } else {
        // exact fallback (pathological ties): R x wave-min over pred-keys
        unsigned cm = 0;
        #pragma unroll
        for (int s = 0; s < 16; ++s)
            if (pred[s]) cm |= (1u << s);
        for (int r = 0; r < R; ++r) {
            unsigned long long lm = ~0ull;
            #pragma unroll
            for (int s = 0; s < 16; ++s)
                if ((cm >> s) & 1u) lm = (k[s] < lm) ? k[s] : lm;
            #pragma unroll
            for (int d = 32; d; d >>= 1) {
                unsigned long long o = __shfl_xor(lm, d, 64);
                lm = (o < lm) ? o : lm;
            }
            bool done = false;
            #pragma unroll
            for (int s = 0; s < 16; ++s) {
                if (!done && ((cm >> s) & 1u) && k[s] == lm) {
                    cm &= ~(1u << s);
                    done = true;
                }
            }
            if (r >= 1 && lane == 0) {
                int q2 = r - 1;
                if (q2 % dil == 0) {
                    int j = q2 / dil;
                    if (j < KNN_K) nbrs[wv][j] = (int)(lm & 0xFFFFFFFFull);
                }
            }
        }
    }
    __threadfence_block();

    // aggregate: lane = channel. Same FP association as previous rounds:
    // acc = self + P0 + P1 + P2 + P3, Pg = sum over j = g, g+4, ...
    {
        const float sc = 1.0f / 21.0f;
        size_t base = ((size_t)b * N + n) * 64;
        float part[4];
        #pragma unroll
        for (int g = 0; g < 4; ++g) {
            float pacc = 0.f;
            for (int j = g; j < KNN_K; j += 4)
                pacc += lin[((size_t)b * N + nbrs[wv][j]) * 64 + lane];
            part[g] = pacc;
        }
        float acc = lin[base + lane] + part[0] + part[1] + part[2] + part[3];
        float v = acc * sc;
        v = (v - mu[lane]) / sqrtf(var[lane] + EPSBN) * gam[lane] + bet[lane];
        v = fmaxf(v, 0.f);
        if (feats_out) feats_out[base + lane] = v;
        if (mode == 0) ms[base + lane] = v;
        else if (mode == 1) ms[base + lane] += v;
        else {
            float m3 = (ms[base + lane] + v) * (1.0f / 3.0f);
            short hh = f2bf(m3);
            msh[base + lane] = hh;
            msl[base + lane] = f2bf(m3 - bf2f(hh));
        }
    }
}

// ---------------- 64x64-tile fp32 GEMM (GCN lin layers) ----------------------
template<int EPI>
__global__ __launch_bounds__(256) void gemm_kernel(
    const float* __restrict__ A, const float* __restrict__ W,
    const float* __restrict__ bias,
    const float* __restrict__ gam, const float* __restrict__ bet,
    const float* __restrict__ mu, const float* __restrict__ var,
    float* __restrict__ C,
    int M, int K, int N)
{
    __shared__ float As[16][68];
    __shared__ float Bs[16][68];
    int tx = threadIdx.x, ty = threadIdx.y;
    int tid = ty * 16 + tx;
    int row0 = blockIdx.y * 64, col0 = blockIdx.x * 64;
    float acc[4][4] = {};
    for (int k0 = 0; k0 < K; k0 += 16) {
        #pragma unroll
        for (int it = 0; it < 4; ++it) {
            int idx = tid + it * 256;
            int r = idx >> 4, kk = idx & 15;
            int gr = row0 + r, gk = k0 + kk;
            As[kk][r] = (gr < M && gk < K) ? A[(size_t)gr * K + gk] : 0.f;
        }
        #pragma unroll
        for (int it = 0; it < 4; ++it) {
            int idx = tid + it * 256;
            int kk = idx >> 6, c = idx & 63;
            int gk = k0 + kk, gc = col0 + c;
            Bs[kk][c] = (gk < K && gc < N) ? W[(size_t)gk * N + gc] : 0.f;
        }
        __syncthreads();
        #pragma unroll
        for (int kk = 0; kk < 16; ++kk) {
            float4 a4 = *reinterpret_cast<const float4*>(&As[kk][ty * 4]);
            float4 b4 = *reinterpret_cast<const float4*>(&Bs[kk][tx * 4]);
            float av[4] = {a4.x, a4.y, a4.z, a4.w};
            float bv[4] = {b4.x, b4.y, b4.z, b4.w};
            #pragma unroll
            for (int i = 0; i < 4; ++i)
                #pragma unroll
                for (int j = 0; j < 4; ++j)
                    acc[i][j] = fmaf(av[i], bv[j], acc[i][j]);
        }
        __syncthreads();
    }
    #pragma unroll
    for (int i = 0; i < 4; ++i) {
        int r = row0 + ty * 4 + i;
        if (r >= M) break;
        #pragma unroll
        for (int j = 0; j < 4; ++j) {
            int c = col0 + tx * 4 + j;
            if (c >= N) continue;
            float val = acc[i][j] + bias[c];
            if (EPI >= 1) {
                val = (val - mu[c]) / sqrtf(var[c] + EPSBN) * gam[c] + bet[c];
                val = fmaxf(val, 0.f);
            }
            C[(size_t)r * N + c] = val;
        }
    }
}

// ---------------- skinny split-K GEMM for M=32 tail layers -------------------
__global__ __launch_bounds__(256) void skinny_gemm_kernel(
    const float* __restrict__ A, const float* __restrict__ W,
    float* __restrict__ part, int K, int N)
{
    __shared__ float Alds[32][260];
    int tid = threadIdx.x;
    int col0 = blockIdx.x * 32;
    int kc = blockIdx.y;
    int k0 = kc * 256;
    #pragma unroll
    for (int it = 0; it < 8; ++it) {
        int idx = tid + it * 256;
        int r = idx >> 6, kq = (idx & 63) * 4;
        f32x4 v = *(const f32x4*)&A[(size_t)r * K + k0 + kq];
        *(f32x4*)&Alds[r][kq] = v;
    }
    __syncthreads();

    int col = col0 + (tid & 31);
    int g = tid >> 5;
    bool colok = col < N;
    const float* Wp = W + (size_t)k0 * N + (colok ? col : 0);
    float acc0 = 0.f, acc1 = 0.f, acc2 = 0.f, acc3 = 0.f;
    #pragma unroll 4
    for (int k = 0; k < 256; ++k) {
        float wv = Wp[(size_t)k * N];
        acc0 = fmaf(Alds[g * 4 + 0][k], wv, acc0);
        acc1 = fmaf(Alds[g * 4 + 1][k], wv, acc1);
        acc2 = fmaf(Alds[g * 4 + 2][k], wv, acc2);
        acc3 = fmaf(Alds[g * 4 + 3][k], wv, acc3);
    }
    if (colok) {
        size_t base = ((size_t)kc * 32 + g * 4) * N + col;
        part[base]         = acc0;
        part[base + N]     = acc1;
        part[base + 2 * N] = acc2;
        part[base + 3 * N] = acc3;
    }
}

template<int EPI>
__global__ void skinny_reduce_kernel(
    const float* __restrict__ part, const float* __restrict__ bias,
    const float* __restrict__ gam, const float* __restrict__ bet,
    const float* __restrict__ mu, const float* __restrict__ var,
    float* __restrict__ C, int M, int N, int kchunks)
{
    int i = blockIdx.x * 256 + threadIdx.x;
    if (i >= M * N) return;
    int c = i % N;
    float s = 0.f;
    for (int kc = 0; kc < kchunks; ++kc) s += part[(size_t)kc * M * N + i];
    float val = s + bias[c];
    if (EPI >= 1) {
        val = (val - mu[c]) / sqrtf(var[c] + EPSBN) * gam[c] + bet[c];
        val = fmaxf(val, 0.f);
    }
    C[i] = val;
}

// ---------------- weight pre-split: W (KxN fp32) -> Bh,Bl ([N][K] bf16) ------
__global__ void split_wt_kernel(const float* __restrict__ W,
                                short* __restrict__ Bh, short* __restrict__ Bl,
                                int K, int N)
{
    int n = blockIdx.x * 64 + threadIdx.x;
    if (n >= N) return;
    for (int k0 = 0; k0 < K; k0 += 8) {
        s16x8 h, l;
        #pragma unroll
        for (int e = 0; e < 8; ++e) {
            float x = W[(size_t)(k0 + e) * N + n];
            short hh = f2bf(x);
            h[e] = hh;
            l[e] = f2bf(x - bf2f(hh));
        }
        *(s16x8*)&Bh[(size_t)n * K + k0] = h;
        *(s16x8*)&Bl[(size_t)n * K + k0] = l;
    }
}

// ---------------- split-bf16 MFMA GEMM, pre-split operands -------------------
// A: hi/lo bf16 [M][K]; B: hi/lo bf16 [N][K] (transposed). 3-term split.
// 1-D grid with XCD-chunked swizzle. Requires (M/128) % 8 == 0.
// EPI: 1 = bias+BN+ReLU -> bf16 hi/lo split store; 2 = bias+BN+ReLU+maxpool
template<int EPI>
__global__ __launch_bounds__(256) void gemm_mfma_kernel(
    const short* __restrict__ Ah, const short* __restrict__ Al,
    const short* __restrict__ Bh, const short* __restrict__ Bl,
    const float* __restrict__ bias,
    const float* __restrict__ gam, const float* __restrict__ bet,
    const float* __restrict__ mu, const float* __restrict__ var,
    short* __restrict__ Chi, short* __restrict__ Clo,
    float* __restrict__ pool,
    int M, int K, int N, int rowsPerBatch)
{
    __shared__ short Alds[128][72];   // [0..31]=hi k, [32..63]=lo k
    __shared__ short Blds[128][72];
    __shared__ int poolS[128];

    int tid = threadIdx.x;
    int wave = tid >> 6, lane = tid & 63;
    int wr = wave >> 1, wc = wave & 1;
    int nx = N >> 7;
    int rowsPerXcd = (M >> 7) >> 3;
    int bid = blockIdx.x;
    int xcd = bid & 7, l = bid >> 3;
    int tileY = xcd * rowsPerXcd + l / nx;
    int tileX = l - (l / nx) * nx;
    int row0 = tileY * 128, col0 = tileX * 128;

    int fr = lane & 15, fq = lane >> 4;
    int kb = fq * 8;

    f32x4 acc[4][4] = {};

    for (int k0 = 0; k0 < K; k0 += 32) {
        #pragma unroll
        for (int it = 0; it < 2; ++it) {
            int idx = tid + it * 256;
            int r = idx >> 2, ch = (idx & 3) * 8;
            size_t go = (size_t)(row0 + r) * K + k0 + ch;
            *(s16x8*)&Alds[r][ch]      = *(const s16x8*)&Ah[go];
            *(s16x8*)&Alds[r][32 + ch] = *(const s16x8*)&Al[go];
        }
        #pragma unroll
        for (int it = 0; it < 2; ++it) {
            int idx = tid + it * 256;
            int c = idx >> 2, ch = (idx & 3) * 8;
            size_t bo = (size_t)(col0 + c) * K + k0 + ch;
            *(s16x8*)&Blds[c][ch]      = *(const s16x8*)&Bh[bo];
            *(s16x8*)&Blds[c][32 + ch] = *(const s16x8*)&Bl[bo];
        }
        __syncthreads();

        s16x8 ah[4], al[4], bhf[4], blf[4];
        #pragma unroll
        for (int i = 0; i < 4; ++i) {
            int r = wr * 64 + i * 16 + fr;
            ah[i] = *(const s16x8*)&Alds[r][kb];
            al[i] = *(const s16x8*)&Alds[r][32 + kb];
        }
        #pragma unroll
        for (int j = 0; j < 4; ++j) {
            int c = wc * 64 + j * 16 + fr;
            bhf[j] = *(const s16x8*)&Blds[c][kb];
            blf[j] = *(const s16x8*)&Blds[c][32 + kb];
        }
        #pragma unroll
        for (int i = 0; i < 4; ++i)
            #pragma unroll
            for (int j = 0; j < 4; ++j) {
                acc[i][j] = __builtin_amdgcn_mfma_f32_16x16x32_bf16(ah[i], bhf[j], acc[i][j], 0, 0, 0);
                acc[i][j] = __builtin_amdgcn_mfma_f32_16x16x32_bf16(ah[i], blf[j], acc[i][j], 0, 0, 0);
                acc[i][j] = __builtin_amdgcn_mfma_f32_16x16x32_bf16(al[i], bhf[j], acc[i][j], 0, 0, 0);
            }
        __syncthreads();
    }

    if (EPI == 1) {
        #pragma unroll
        for (int j = 0; j < 4; ++j) {
            int col = col0 + wc * 64 + j * 16 + fr;
            float bs = bias[col], g = gam[col], be = bet[col], m = mu[col];
            float inv = 1.0f / sqrtf(var[col] + EPSBN);
            #pragma unroll
            for (int i = 0; i < 4; ++i) {
                int rbase = row0 + wr * 64 + i * 16 + fq * 4;
                #pragma unroll
                for (int reg = 0; reg < 4; ++reg) {
                    float val = acc[i][j][reg] + bs;
                    val = (val - m) * inv * g + be;
                    val = fmaxf(val, 0.f);
                    short hh = f2bf(val);
                    size_t o = (size_t)(rbase + reg) * N + col;
                    Chi[o] = hh;
                    Clo[o] = f2bf(val - bf2f(hh));
                }
            }
        }
    } else {
        float cmax[4];
        #pragma unroll
        for (int j = 0; j < 4; ++j) {
            int col = col0 + wc * 64 + j * 16 + fr;
            float bs = bias[col], g = gam[col], be = bet[col], m = mu[col];
            float inv = 1.0f / sqrtf(var[col] + EPSBN);
            float cm = 0.f;
            #pragma unroll
            for (int i = 0; i < 4; ++i)
                #pragma unroll
                for (int reg = 0; reg < 4; ++reg) {
                    float val = acc[i][j][reg] + bs;
                    val = (val - m) * inv * g + be;
                    val = fmaxf(val, 0.f);
                    cm = fmaxf(cm, val);
                }
            cmax[j] = cm;
        }
        #pragma unroll
        for (int j = 0; j < 4; ++j) {
            cmax[j] = fmaxf(cmax[j], __shfl_xor(cmax[j], 16, 64));
            cmax[j] = fmaxf(cmax[j], __shfl_xor(cmax[j], 32, 64));
        }
        if (tid < 128) poolS[tid] = 0;
        __syncthreads();
        if (fq == 0) {
            #pragma unroll
            for (int j = 0; j < 4; ++j)
                atomicMax(&poolS[wc * 64 + j * 16 + fr], __float_as_int(cmax[j]));
        }
        __syncthreads();
        if (tid < 128) {
            int bb = row0 / rowsPerBatch;
            atomicMax((int*)&pool[(size_t)bb * N + col0 + tid], poolS[tid]);
        }
    }
}

extern "C" void kernel_launch(void* const* d_in, const int* in_sizes, int n_in,
                              void* d_out, int out_size, void* d_ws, size_t ws_size,
                              hipStream_t stream)
{
    (void)in_sizes; (void)n_in; (void)out_size;
    const int B = 32, N = 1024, MBN = B * N;
    const float* x = (const float*)d_in[0];

    const float *Wg[3], *bg[3], *gg[3], *gb[3], *gm[3], *gv[3];
    for (int i = 0; i < 3; ++i) {
        int base = 1 + i * 6;
        Wg[i] = (const float*)d_in[base + 0];
        bg[i] = (const float*)d_in[base + 1];
        gg[i] = (const float*)d_in[base + 2];
        gb[i] = (const float*)d_in[base + 3];
        gm[i] = (const float*)d_in[base + 4];
        gv[i] = (const float*)d_in[base + 5];
    }
    const float *Wm[5], *bm[5], *ng[5], *nb[5], *nm[5], *nv[5];
    for (int i = 0; i < 5; ++i) {
        int base = 19 + i * 6;
        Wm[i] = (const float*)d_in[base + 0];
        bm[i] = (const float*)d_in[base + 1];
        ng[i] = (const float*)d_in[base + 2];
        nb[i] = (const float*)d_in[base + 3];
        nm[i] = (const float*)d_in[base + 4];
        nv[i] = (const float*)d_in[base + 5];
    }
    const float* W6 = (const float*)d_in[49];
    const float* b6 = (const float*)d_in[50];

    // ---- workspace layout (256B-aligned; distB aliases f1h/f1l/f2h/f2l) ----
    char* w = (char*)d_ws;
    size_t off = 0;
    auto allocB = [&](size_t bytes) {
        void* p = w + off;
        off += (bytes + 255) & ~(size_t)255;
        return p;
    };
    float* ms     = (float*)allocB((size_t)MBN * 64 * 4);
    float* fA     = (float*)allocB((size_t)MBN * 64 * 4);
    float* fB     = (float*)allocB((size_t)MBN * 64 * 4);
    float* lin    = (float*)allocB((size_t)MBN * 64 * 4);
    float* sqv    = (float*)allocB((size_t)MBN * 4);
    float* pooled = (float*)allocB((size_t)B * 1024 * 4);
    float* f4     = (float*)allocB((size_t)B * 1024 * 4);
    float* f5     = (float*)allocB((size_t)B * 512 * 4);
    float* skpart = (float*)allocB((size_t)4 * 32 * 1024 * 4);
    short* msh    = (short*)allocB((size_t)MBN * 64 * 2);
    short* msl    = (short*)allocB((size_t)MBN * 64 * 2);
    short* w1h    = (short*)allocB((size_t)64 * 128 * 2);
    short* w1l    = (short*)allocB((size_t)64 * 128 * 2);
    short* w2h    = (short*)allocB((size_t)128 * 512 * 2);
    short* w2l    = (short*)allocB((size_t)128 * 512 * 2);
    short* w3h    = (short*)allocB((size_t)512 * 1024 * 2);
    short* w3l    = (short*)allocB((size_t)512 * 1024 * 2);
    size_t bigOff = off;
    short* f1h = (short*)(w + bigOff);
    short* f1l = (short*)(w + bigOff + 1 * (size_t)MBN * 128 * 2);
    short* f2h = (short*)(w + bigOff + 2 * (size_t)MBN * 128 * 2);
    short* f2l = (short*)(w + bigOff + 2 * (size_t)MBN * 128 * 2 + (size_t)MBN * 512 * 2);
    float* distB = (float*)(w + bigOff);
    size_t distBytes = (size_t)N * N * sizeof(float);
    int chunkB = 1;
    if (ws_size > bigOff) {
        size_t cap = (ws_size - bigOff) / distBytes;
        chunkB = (int)(cap < 32 ? cap : 32);
        if (chunkB < 1) chunkB = 1;
    }

    dim3 blk16(16, 16);
    auto grid64  = [](int M, int Nn) { return dim3((unsigned)((Nn + 63) / 64), (unsigned)((M + 63) / 64)); };
    auto gridMf1 = [](int M, int Nn) { return dim3((unsigned)((Nn / 128) * (M / 128))); };

    // ---- weight splits ----
    split_wt_kernel<<<dim3(128 / 64), 64, 0, stream>>>(Wm[0], w1h, w1l, 64, 128);
    split_wt_kernel<<<dim3(512 / 64), 64, 0, stream>>>(Wm[1], w2h, w2l, 128, 512);
    split_wt_kernel<<<dim3(1024 / 64), 64, 0, stream>>>(Wm[2], w3h, w3l, 512, 1024);

    // ---- 3 GCN layers (exact fp32; selection-sensitive) ----
    const float* featsIn = x;
    float* featsOutArr[3] = { fA, fB, nullptr };
    int Cin[3] = { 3, 64, 64 };
    int dils[3] = { 1, 2, 4 };
    for (int L = 0; L < 3; ++L) {
        sq_kernel<<<(MBN + 255) / 256, 256, 0, stream>>>(featsIn, sqv, MBN, Cin[L]);
        gemm_kernel<0><<<grid64(MBN, 64), blk16, 0, stream>>>(
            featsIn, Wg[L], bg[L], nullptr, nullptr, nullptr, nullptr,
            lin, MBN, Cin[L], 64);
        for (int b0 = 0; b0 < B; b0 += chunkB) {
            int cb = (B - b0 < chunkB) ? (B - b0) : chunkB;
            dist128t_kernel<<<dim3(36, 1, (unsigned)cb), 256, 0, stream>>>(
                featsIn, sqv, distB, b0, N, Cin[L]);
            knn_agg_wave_kernel<<<cb * N / 4, 256, 0, stream>>>(
                distB, lin, gg[L], gb[L], gm[L], gv[L],
                featsOutArr[L], ms, msh, msl, b0, N, dils[L], L);
        }
        featsIn = featsOutArr[L];
    }

    // ---- MLP tail: split-bf16 MFMA (pre-split operands, XCD swizzle) ----
    gemm_mfma_kernel<1><<<gridMf1(MBN, 128), 256, 0, stream>>>(
        msh, msl, w1h, w1l, bm[0], ng[0], nb[0], nm[0], nv[0],
        f1h, f1l, nullptr, MBN, 64, 128, N);
    gemm_mfma_kernel<1><<<gridMf1(MBN, 512), 256, 0, stream>>>(
        f1h, f1l, w2h, w2l, bm[1], ng[1], nb[1], nm[1], nv[1],
        f2h, f2l, nullptr, MBN, 128, 512, N);
    hipMemsetAsync(pooled, 0, (size_t)B * 1024 * sizeof(float), stream);
    gemm_mfma_kernel<2><<<gridMf1(MBN, 1024), 256, 0, stream>>>(
        f2h, f2l, w3h, w3l, bm[2], ng[2], nb[2], nm[2], nv[2],
        nullptr, nullptr, pooled, MBN, 512, 1024, N);

    // ---- M=32 tail layers: skinny split-K + reduce ----
    skinny_gemm_kernel<<<dim3(1024 / 32, 4), 256, 0, stream>>>(pooled, Wm[3], skpart, 1024, 1024);
    skinny_reduce_kernel<1><<<(32 * 1024 + 255) / 256, 256, 0, stream>>>(
        skpart, bm[3], ng[3], nb[3], nm[3], nv[3], f4, 32, 1024, 4);
    skinny_gemm_kernel<<<dim3(512 / 32, 4), 256, 0, stream>>>(f4, Wm[4], skpart, 1024, 512);
    skinny_reduce_kernel<1><<<(32 * 512 + 255) / 256, 256, 0, stream>>>(
        skpart, bm[4], ng[4], nb[4], nm[4], nv[4], f5, 32, 512, 4);
    skinny_gemm_kernel<<<dim3(2, 2), 256, 0, stream>>>(f5, W6, skpart, 512, 40);
    skinny_reduce_kernel<0><<<(32 * 40 + 255) / 256, 256, 0, stream>>>(
        skpart, b6, nullptr, nullptr, nullptr, nullptr, (float*)d_out, 32, 40, 2);
}

// Round 10
// 689.463 us; speedup vs baseline: 1.0256x; 1.0256x over previous
//
#include <hip/hip_runtime.h>
#include <stdint.h>

#define KNN_K 20
#define EPSBN 1e-5f

typedef __attribute__((ext_vector_type(4))) float f32x4;
typedef __attribute__((ext_vector_type(8))) short s16x8;
typedef __attribute__((ext_vector_type(4))) short s16x4;

__device__ __forceinline__ unsigned sortable_f32(float f) {
    unsigned u = __float_as_uint(f);
    return (u & 0x80000000u) ? ~u : (u | 0x80000000u);
}

// round-to-nearest-even float -> bf16 bit pattern
__device__ __forceinline__ short f2bf(float x) {
    unsigned u = __float_as_uint(x);
    unsigned r = (u + 0x7fffu + ((u >> 16) & 1u)) >> 16;
    return (short)r;
}
__device__ __forceinline__ float bf2f(short h) {
    return __uint_as_float(((unsigned)(unsigned short)h) << 16);
}

// ---------------- per-point squared norm ----------------
__global__ void sq_kernel(const float* __restrict__ x, float* __restrict__ sq,
                          int total, int C) {
    int i = blockIdx.x * 256 + threadIdx.x;
    if (i >= total) return;
    const float* p = x + (size_t)i * C;
    float s = 0.f;
    for (int c = 0; c < C; ++c) s += p[c] * p[c];
    sq[i] = s;
}

// ---------------- pairwise squared distances, triangular 128x128 tiles ------
// Computes only tiles bi<=bj (36 of 64) and mirror-writes the transpose.
// EXACT: fp32 add/mul are commutative bitwise; k-ascending fmaf chain is
// identical for (n,m) and (m,n).
__global__ __launch_bounds__(256) void dist128t_kernel(
    const float* __restrict__ feats, const float* __restrict__ sq,
    float* __restrict__ dist, int b0, int N, int C)
{
    int lb = blockIdx.z;
    int b = b0 + lb;
    const float* F = feats + (size_t)b * N * C;
    const float* S = sq + (size_t)b * N;
    float* D = dist + (size_t)lb * N * N;
    int t = blockIdx.x, bi = 0;
    while (t >= 8 - bi) { t -= 8 - bi; ++bi; }
    int bj = bi + t;
    int n0 = bi * 128, m0 = bj * 128;

    __shared__ float As[16][132];
    __shared__ float Bs[16][132];
    int tx = threadIdx.x & 15, ty = threadIdx.x >> 4;
    int tid = threadIdx.x;
    float acc[8][8] = {};
    for (int k0 = 0; k0 < C; k0 += 16) {
        #pragma unroll
        for (int it = 0; it < 8; ++it) {
            int idx = tid + it * 256;
            int r = idx >> 4, kk = idx & 15;
            int gk = k0 + kk;
            As[kk][r] = (gk < C) ? F[(size_t)(n0 + r) * C + gk] : 0.f;
            Bs[kk][r] = (gk < C) ? F[(size_t)(m0 + r) * C + gk] : 0.f;
        }
        __syncthreads();
        #pragma unroll
        for (int kk = 0; kk < 16; ++kk) {
            float4 a0 = *reinterpret_cast<const float4*>(&As[kk][ty * 4]);
            float4 a1 = *reinterpret_cast<const float4*>(&As[kk][64 + ty * 4]);
            float4 b0 = *reinterpret_cast<const float4*>(&Bs[kk][tx * 4]);
            float4 b1 = *reinterpret_cast<const float4*>(&Bs[kk][64 + tx * 4]);
            float av[8] = {a0.x, a0.y, a0.z, a0.w, a1.x, a1.y, a1.z, a1.w};
            float bv[8] = {b0.x, b0.y, b0.z, b0.w, b1.x, b1.y, b1.z, b1.w};
            #pragma unroll
            for (int i = 0; i < 8; ++i)
                #pragma unroll
                for (int j = 0; j < 8; ++j)
                    acc[i][j] = fmaf(av[i], bv[j], acc[i][j]);
        }
        __syncthreads();
    }
    #pragma unroll
    for (int i = 0; i < 8; ++i) {
        int n = n0 + ((i < 4) ? ty * 4 + i : 64 + ty * 4 + (i - 4));
        float sn = S[n];
        #pragma unroll
        for (int j = 0; j < 8; ++j) {
            int m = m0 + ((j < 4) ? tx * 4 + j : 64 + tx * 4 + (j - 4));
            D[(size_t)n * N + m] = (sn + S[m]) - 2.0f * acc[i][j];
        }
    }
    if (bi < bj) {
        #pragma unroll
        for (int j = 0; j < 8; ++j) {
            int m = m0 + ((j < 4) ? tx * 4 + j : 64 + tx * 4 + (j - 4));
            float sm = S[m];
            #pragma unroll
            for (int i = 0; i < 8; ++i) {
                int n = n0 + ((i < 4) ? ty * 4 + i : 64 + ty * 4 + (i - 4));
                D[(size_t)m * N + n] = (sm + S[n]) - 2.0f * acc[i][j];
            }
        }
    }
}

// ---------------- wave-per-point KNN select + aggregate + BN + ReLU ---------
// 4 points per 256-thread block, one wave each. No block barriers.
// (R8 version — reverted: single-level histogram + LDS-counter compaction.
//  R9's ballot compaction + 2-level refine measured -18us net; see journal.)
// mode: 0 ms=val, 1 ms+=val, 2 final mean -> bf16 hi/lo split (msh/msl)
__global__ __launch_bounds__(256) void knn_agg_wave_kernel(
    const float* __restrict__ dist, const float* __restrict__ lin,
    const float* __restrict__ gam, const float* __restrict__ bet,
    const float* __restrict__ mu, const float* __restrict__ var,
    float* __restrict__ feats_out, float* __restrict__ ms,
    short* __restrict__ msh, short* __restrict__ msl,
    int b0, int N, int dil, int mode)
{
    // per-point LDS: packed u16x2 histogram (2048 bins), candidates, nbrs
    __shared__ alignas(16) unsigned hist[4][1024];
    __shared__ unsigned long long cand[4][256];
    __shared__ int nbrs[4][KNN_K];
    __shared__ int cnts[4];

    int tid = threadIdx.x;
    int wv = tid >> 6, lane = tid & 63;
    int p = blockIdx.x * 4 + wv;
    int lb = p / N, n = p - lb * N;
    int b = b0 + lb;
    const int R = KNN_K * dil + 1;   // smallest keys needed (incl self)

    // load 16 distances/lane (coalesced float4), build sortable keys in regs
    const float* drow = dist + ((size_t)lb * N + n) * N;
    const f32x4* drow4 = (const f32x4*)drow;
    unsigned long long k[16];
    #pragma unroll
    for (int s = 0; s < 4; ++s) {
        f32x4 v = drow4[s * 64 + lane];
        #pragma unroll
        for (int e = 0; e < 4; ++e) {
            int m = (s * 64 + lane) * 4 + e;
            k[s * 4 + e] = ((unsigned long long)sortable_f32(v[e]) << 32) | (unsigned)m;
        }
    }
    // zero histogram (1024 words / wave)
    unsigned* H = hist[wv];
    {
        uint4 z = {0u, 0u, 0u, 0u};
        #pragma unroll
        for (int i = 0; i < 4; ++i) *(uint4*)&H[lane * 16 + i * 4] = z;
    }
    if (lane == 0) cnts[wv] = 0;
    __threadfence_block();
    // histogram on top 11 bits (bin d -> word d>>1, half d&1)
    #pragma unroll
    for (int s = 0; s < 16; ++s) {
        unsigned d = (unsigned)(k[s] >> 53);
        atomicAdd(&H[d >> 1], 1u << ((d & 1) << 4));
    }
    __threadfence_block();
    // per-lane 32-bin segment count + wave inclusive scan
    unsigned w[16];
    #pragma unroll
    for (int i = 0; i < 4; ++i) *(uint4*)&w[i * 4] = *(const uint4*)&H[lane * 16 + i * 4];
    int psum = 0;
    #pragma unroll
    for (int i = 0; i < 16; ++i) psum += (int)(w[i] & 0xFFFFu) + (int)(w[i] >> 16);
    int incl = psum;
    #pragma unroll
    for (int d = 1; d < 64; d <<= 1) {
        int o = __shfl_up(incl, d, 64);
        if (lane >= d) incl += o;
    }
    int excl = incl - psum;
    // pivot bin within the lane whose segment crosses R
    int svDl = 0, c0l = 0, pl = 0;
    bool found = (excl < R && incl >= R);
    if (found) {
        int cum = excl;
        #pragma unroll
        for (int i = 0; i < 32; ++i) {
            int hv = (i & 1) ? (int)(w[i >> 1] >> 16) : (int)(w[i >> 1] & 0xFFFFu);
            if (cum + hv >= R) { svDl = lane * 32 + i; c0l = cum; pl = hv; break; }
            cum += hv;
        }
    }
    unsigned long long fm = __ballot(found);
    int src = __ffsll(fm) - 1;
    int svD  = __shfl(svDl, src, 64);
    int svC0 = __shfl(c0l, src, 64);
    int svP  = __shfl(pl, src, 64);
    int Cnt = svC0 + svP;            // exact count of keys with digit <= pivot

    if (Cnt <= 256) {
        // compact candidates
        #pragma unroll
        for (int s = 0; s < 16; ++s) {
            if ((unsigned)(k[s] >> 53) <= (unsigned)svD) {
                int pos = atomicAdd(&cnts[wv], 1);
                cand[wv][pos] = k[s];
            }
        }
        __threadfence_block();
        // owned candidates (up to 4/lane); single-pass 4-way rank
        unsigned long long my[4];
        #pragma unroll
        for (int q = 0; q < 4; ++q) {
            int slot = lane + q * 64;
            my[q] = (slot < Cnt) ? cand[wv][slot] : ~0ull;
        }
        int r0 = 0, r1 = 0, r2 = 0, r3 = 0;
        for (int c = 0; c < Cnt; ++c) {
            unsigned long long v = cand[wv][c];
            r0 += (v < my[0]) ? 1 : 0;
            r1 += (v < my[1]) ? 1 : 0;
            r2 += (v < my[2]) ? 1 : 0;
            r3 += (v < my[3]) ? 1 : 0;
        }
        int rr[4] = {r0, r1, r2, r3};
        #pragma unroll
        for (int q = 0; q < 4; ++q) {
            int slot = lane + q * 64;
            if (slot < Cnt && rr[q] >= 1) {
                int q2 = rr[q] - 1;
                if (q2 % dil == 0) {
                    int j = q2 / dil;
                    if (j < KNN_K) nbrs[wv][j] = (int)(my[q] & 0xFFFFFFFFull);
                }
            }
        }
    } else {
        // exact fallback (pathological ties): R x wave-min extraction from regs
        unsigned cm = 0;
        #pragma unroll
        for (int s = 0; s < 16; ++s)
            if ((unsigned)(k[s] >> 53) <= (unsigned)svD) cm |= (1u << s);
        for (int r = 0; r < R; ++r) {
            unsigned long long lm = ~0ull;
            #pragma unroll
            for (int s = 0; s < 16; ++s)
                if ((cm >> s) & 1u) lm = (k[s] < lm) ? k[s] : lm;
            #pragma unroll
            for (int d = 32; d; d >>= 1) {
                unsigned long long o = __shfl_xor(lm, d, 64);
                lm = (o < lm) ? o : lm;
            }
            bool done = false;
            #pragma unroll
            for (int s = 0; s < 16; ++s) {
                if (!done && ((cm >> s) & 1u) && k[s] == lm) {
                    cm &= ~(1u << s);
                    done = true;
                }
            }
            if (r >= 1 && lane == 0) {
                int q2 = r - 1;
                if (q2 % dil == 0) {
                    int j = q2 / dil;
                    if (j < KNN_K) nbrs[wv][j] = (int)(lm & 0xFFFFFFFFull);
                }
            }
        }
    }
    __threadfence_block();

    // aggregate: lane = channel. Same FP association as previous rounds:
    // acc = self + P0 + P1 + P2 + P3, Pg = sum over j = g, g+4, ...
    {
        const float sc = 1.0f / 21.0f;
        size_t base = ((size_t)b * N + n) * 64;
        float part[4];
        #pragma unroll
        for (int g = 0; g < 4; ++g) {
            float pacc = 0.f;
            for (int j = g; j < KNN_K; j += 4)
                pacc += lin[((size_t)b * N + nbrs[wv][j]) * 64 + lane];
            part[g] = pacc;
        }
        float acc = lin[base + lane] + part[0] + part[1] + part[2] + part[3];
        float v = acc * sc;
        v = (v - mu[lane]) / sqrtf(var[lane] + EPSBN) * gam[lane] + bet[lane];
        v = fmaxf(v, 0.f);
        if (feats_out) feats_out[base + lane] = v;
        if (mode == 0) ms[base + lane] = v;
        else if (mode == 1) ms[base + lane] += v;
        else {
            float m3 = (ms[base + lane] + v) * (1.0f / 3.0f);
            short hh = f2bf(m3);
            msh[base + lane] = hh;
            msl[base + lane] = f2bf(m3 - bf2f(hh));
        }
    }
}

// ---------------- 64x64-tile fp32 GEMM (GCN lin layers) ----------------------
template<int EPI>
__global__ __launch_bounds__(256) void gemm_kernel(
    const float* __restrict__ A, const float* __restrict__ W,
    const float* __restrict__ bias,
    const float* __restrict__ gam, const float* __restrict__ bet,
    const float* __restrict__ mu, const float* __restrict__ var,
    float* __restrict__ C,
    int M, int K, int N)
{
    __shared__ float As[16][68];
    __shared__ float Bs[16][68];
    int tx = threadIdx.x, ty = threadIdx.y;
    int tid = ty * 16 + tx;
    int row0 = blockIdx.y * 64, col0 = blockIdx.x * 64;
    float acc[4][4] = {};
    for (int k0 = 0; k0 < K; k0 += 16) {
        #pragma unroll
        for (int it = 0; it < 4; ++it) {
            int idx = tid + it * 256;
            int r = idx >> 4, kk = idx & 15;
            int gr = row0 + r, gk = k0 + kk;
            As[kk][r] = (gr < M && gk < K) ? A[(size_t)gr * K + gk] : 0.f;
        }
        #pragma unroll
        for (int it = 0; it < 4; ++it) {
            int idx = tid + it * 256;
            int kk = idx >> 6, c = idx & 63;
            int gk = k0 + kk, gc = col0 + c;
            Bs[kk][c] = (gk < K && gc < N) ? W[(size_t)gk * N + gc] : 0.f;
        }
        __syncthreads();
        #pragma unroll
        for (int kk = 0; kk < 16; ++kk) {
            float4 a4 = *reinterpret_cast<const float4*>(&As[kk][ty * 4]);
            float4 b4 = *reinterpret_cast<const float4*>(&Bs[kk][tx * 4]);
            float av[4] = {a4.x, a4.y, a4.z, a4.w};
            float bv[4] = {b4.x, b4.y, b4.z, b4.w};
            #pragma unroll
            for (int i = 0; i < 4; ++i)
                #pragma unroll
                for (int j = 0; j < 4; ++j)
                    acc[i][j] = fmaf(av[i], bv[j], acc[i][j]);
        }
        __syncthreads();
    }
    #pragma unroll
    for (int i = 0; i < 4; ++i) {
        int r = row0 + ty * 4 + i;
        if (r >= M) break;
        #pragma unroll
        for (int j = 0; j < 4; ++j) {
            int c = col0 + tx * 4 + j;
            if (c >= N) continue;
            float val = acc[i][j] + bias[c];
            if (EPI >= 1) {
                val = (val - mu[c]) / sqrtf(var[c] + EPSBN) * gam[c] + bet[c];
                val = fmaxf(val, 0.f);
            }
            C[(size_t)r * N + c] = val;
        }
    }
}

// ---------------- skinny split-K GEMM for M=32 tail layers -------------------
__global__ __launch_bounds__(256) void skinny_gemm_kernel(
    const float* __restrict__ A, const float* __restrict__ W,
    float* __restrict__ part, int K, int N)
{
    __shared__ float Alds[32][260];
    int tid = threadIdx.x;
    int col0 = blockIdx.x * 32;
    int kc = blockIdx.y;
    int k0 = kc * 256;
    #pragma unroll
    for (int it = 0; it < 8; ++it) {
        int idx = tid + it * 256;
        int r = idx >> 6, kq = (idx & 63) * 4;
        f32x4 v = *(const f32x4*)&A[(size_t)r * K + k0 + kq];
        *(f32x4*)&Alds[r][kq] = v;
    }
    __syncthreads();

    int col = col0 + (tid & 31);
    int g = tid >> 5;
    bool colok = col < N;
    const float* Wp = W + (size_t)k0 * N + (colok ? col : 0);
    float acc0 = 0.f, acc1 = 0.f, acc2 = 0.f, acc3 = 0.f;
    #pragma unroll 4
    for (int k = 0; k < 256; ++k) {
        float wv = Wp[(size_t)k * N];
        acc0 = fmaf(Alds[g * 4 + 0][k], wv, acc0);
        acc1 = fmaf(Alds[g * 4 + 1][k], wv, acc1);
        acc2 = fmaf(Alds[g * 4 + 2][k], wv, acc2);
        acc3 = fmaf(Alds[g * 4 + 3][k], wv, acc3);
    }
    if (colok) {
        size_t base = ((size_t)kc * 32 + g * 4) * N + col;
        part[base]         = acc0;
        part[base + N]     = acc1;
        part[base + 2 * N] = acc2;
        part[base + 3 * N] = acc3;
    }
}

template<int EPI>
__global__ void skinny_reduce_kernel(
    const float* __restrict__ part, const float* __restrict__ bias,
    const float* __restrict__ gam, const float* __restrict__ bet,
    const float* __restrict__ mu, const float* __restrict__ var,
    float* __restrict__ C, int M, int N, int kchunks)
{
    int i = blockIdx.x * 256 + threadIdx.x;
    if (i >= M * N) return;
    int c = i % N;
    float s = 0.f;
    for (int kc = 0; kc < kchunks; ++kc) s += part[(size_t)kc * M * N + i];
    float val = s + bias[c];
    if (EPI >= 1) {
        val = (val - mu[c]) / sqrtf(var[c] + EPSBN) * gam[c] + bet[c];
        val = fmaxf(val, 0.f);
    }
    C[i] = val;
}

// ---------------- weight pre-split: W (KxN fp32) -> Bh,Bl ([N][K] bf16) ------
__global__ void split_wt_kernel(const float* __restrict__ W,
                                short* __restrict__ Bh, short* __restrict__ Bl,
                                int K, int N)
{
    int n = blockIdx.x * 64 + threadIdx.x;
    if (n >= N) return;
    for (int k0 = 0; k0 < K; k0 += 8) {
        s16x8 h, l;
        #pragma unroll
        for (int e = 0; e < 8; ++e) {
            float x = W[(size_t)(k0 + e) * N + n];
            short hh = f2bf(x);
            h[e] = hh;
            l[e] = f2bf(x - bf2f(hh));
        }
        *(s16x8*)&Bh[(size_t)n * K + k0] = h;
        *(s16x8*)&Bl[(size_t)n * K + k0] = l;
    }
}

// ---------------- split-bf16 MFMA GEMM, pre-split operands -------------------
// A: hi/lo bf16 [M][K]; B: hi/lo bf16 [N][K] (transposed). 3-term split.
// 1-D grid with XCD-chunked swizzle. Requires (M/128) % 8 == 0.
// EPI: 1 = bias+BN+ReLU -> bf16 hi/lo split store; 2 = bias+BN+ReLU+maxpool
template<int EPI>
__global__ __launch_bounds__(256) void gemm_mfma_kernel(
    const short* __restrict__ Ah, const short* __restrict__ Al,
    const short* __restrict__ Bh, const short* __restrict__ Bl,
    const float* __restrict__ bias,
    const float* __restrict__ gam, const float* __restrict__ bet,
    const float* __restrict__ mu, const float* __restrict__ var,
    short* __restrict__ Chi, short* __restrict__ Clo,
    float* __restrict__ pool,
    int M, int K, int N, int rowsPerBatch)
{
    __shared__ short Alds[128][72];   // [0..31]=hi k, [32..63]=lo k
    __shared__ short Blds[128][72];
    __shared__ int poolS[128];

    int tid = threadIdx.x;
    int wave = tid >> 6, lane = tid & 63;
    int wr = wave >> 1, wc = wave & 1;
    int nx = N >> 7;
    int rowsPerXcd = (M >> 7) >> 3;
    int bid = blockIdx.x;
    int xcd = bid & 7, l = bid >> 3;
    int tileY = xcd * rowsPerXcd + l / nx;
    int tileX = l - (l / nx) * nx;
    int row0 = tileY * 128, col0 = tileX * 128;

    int fr = lane & 15, fq = lane >> 4;
    int kb = fq * 8;

    f32x4 acc[4][4] = {};

    for (int k0 = 0; k0 < K; k0 += 32) {
        #pragma unroll
        for (int it = 0; it < 2; ++it) {
            int idx = tid + it * 256;
            int r = idx >> 2, ch = (idx & 3) * 8;
            size_t go = (size_t)(row0 + r) * K + k0 + ch;
            *(s16x8*)&Alds[r][ch]      = *(const s16x8*)&Ah[go];
            *(s16x8*)&Alds[r][32 + ch] = *(const s16x8*)&Al[go];
        }
        #pragma unroll
        for (int it = 0; it < 2; ++it) {
            int idx = tid + it * 256;
            int c = idx >> 2, ch = (idx & 3) * 8;
            size_t bo = (size_t)(col0 + c) * K + k0 + ch;
            *(s16x8*)&Blds[c][ch]      = *(const s16x8*)&Bh[bo];
            *(s16x8*)&Blds[c][32 + ch] = *(const s16x8*)&Bl[bo];
        }
        __syncthreads();

        s16x8 ah[4], al[4], bhf[4], blf[4];
        #pragma unroll
        for (int i = 0; i < 4; ++i) {
            int r = wr * 64 + i * 16 + fr;
            ah[i] = *(const s16x8*)&Alds[r][kb];
            al[i] = *(const s16x8*)&Alds[r][32 + kb];
        }
        #pragma unroll
        for (int j = 0; j < 4; ++j) {
            int c = wc * 64 + j * 16 + fr;
            bhf[j] = *(const s16x8*)&Blds[c][kb];
            blf[j] = *(const s16x8*)&Blds[c][32 + kb];
        }
        #pragma unroll
        for (int i = 0; i < 4; ++i)
            #pragma unroll
            for (int j = 0; j < 4; ++j) {
                acc[i][j] = __builtin_amdgcn_mfma_f32_16x16x32_bf16(ah[i], bhf[j], acc[i][j], 0, 0, 0);
                acc[i][j] = __builtin_amdgcn_mfma_f32_16x16x32_bf16(ah[i], blf[j], acc[i][j], 0, 0, 0);
                acc[i][j] = __builtin_amdgcn_mfma_f32_16x16x32_bf16(al[i], bhf[j], acc[i][j], 0, 0, 0);
            }
        __syncthreads();
    }

    if (EPI == 1) {
        #pragma unroll
        for (int j = 0; j < 4; ++j) {
            int col = col0 + wc * 64 + j * 16 + fr;
            float bs = bias[col], g = gam[col], be = bet[col], m = mu[col];
            float inv = 1.0f / sqrtf(var[col] + EPSBN);
            #pragma unroll
            for (int i = 0; i < 4; ++i) {
                int rbase = row0 + wr * 64 + i * 16 + fq * 4;
                #pragma unroll
                for (int reg = 0; reg < 4; ++reg) {
                    float val = acc[i][j][reg] + bs;
                    val = (val - m) * inv * g + be;
                    val = fmaxf(val, 0.f);
                    short hh = f2bf(val);
                    size_t o = (size_t)(rbase + reg) * N + col;
                    Chi[o] = hh;
                    Clo[o] = f2bf(val - bf2f(hh));
                }
            }
        }
    } else {
        float cmax[4];
        #pragma unroll
        for (int j = 0; j < 4; ++j) {
            int col = col0 + wc * 64 + j * 16 + fr;
            float bs = bias[col], g = gam[col], be = bet[col], m = mu[col];
            float inv = 1.0f / sqrtf(var[col] + EPSBN);
            float cm = 0.f;
            #pragma unroll
            for (int i = 0; i < 4; ++i)
                #pragma unroll
                for (int reg = 0; reg < 4; ++reg) {
                    float val = acc[i][j][reg] + bs;
                    val = (val - m) * inv * g + be;
                    val = fmaxf(val, 0.f);
                    cm = fmaxf(cm, val);
                }
            cmax[j] = cm;
        }
        #pragma unroll
        for (int j = 0; j < 4; ++j) {
            cmax[j] = fmaxf(cmax[j], __shfl_xor(cmax[j], 16, 64));
            cmax[j] = fmaxf(cmax[j], __shfl_xor(cmax[j], 32, 64));
        }
        if (tid < 128) poolS[tid] = 0;
        __syncthreads();
        if (fq == 0) {
            #pragma unroll
            for (int j = 0; j < 4; ++j)
                atomicMax(&poolS[wc * 64 + j * 16 + fr], __float_as_int(cmax[j]));
        }
        __syncthreads();
        if (tid < 128) {
            int bb = row0 / rowsPerBatch;
            atomicMax((int*)&pool[(size_t)bb * N + col0 + tid], poolS[tid]);
        }
    }
}

extern "C" void kernel_launch(void* const* d_in, const int* in_sizes, int n_in,
                              void* d_out, int out_size, void* d_ws, size_t ws_size,
                              hipStream_t stream)
{
    (void)in_sizes; (void)n_in; (void)out_size;
    const int B = 32, N = 1024, MBN = B * N;
    const float* x = (const float*)d_in[0];

    const float *Wg[3], *bg[3], *gg[3], *gb[3], *gm[3], *gv[3];
    for (int i = 0; i < 3; ++i) {
        int base = 1 + i * 6;
        Wg[i] = (const float*)d_in[base + 0];
        bg[i] = (const float*)d_in[base + 1];
        gg[i] = (const float*)d_in[base + 2];
        gb[i] = (const float*)d_in[base + 3];
        gm[i] = (const float*)d_in[base + 4];
        gv[i] = (const float*)d_in[base + 5];
    }
    const float *Wm[5], *bm[5], *ng[5], *nb[5], *nm[5], *nv[5];
    for (int i = 0; i < 5; ++i) {
        int base = 19 + i * 6;
        Wm[i] = (const float*)d_in[base + 0];
        bm[i] = (const float*)d_in[base + 1];
        ng[i] = (const float*)d_in[base + 2];
        nb[i] = (const float*)d_in[base + 3];
        nm[i] = (const float*)d_in[base + 4];
        nv[i] = (const float*)d_in[base + 5];
    }
    const float* W6 = (const float*)d_in[49];
    const float* b6 = (const float*)d_in[50];

    // ---- workspace layout (256B-aligned; distB aliases f1h/f1l/f2h/f2l) ----
    char* w = (char*)d_ws;
    size_t off = 0;
    auto allocB = [&](size_t bytes) {
        void* p = w + off;
        off += (bytes + 255) & ~(size_t)255;
        return p;
    };
    float* ms     = (float*)allocB((size_t)MBN * 64 * 4);
    float* fA     = (float*)allocB((size_t)MBN * 64 * 4);
    float* fB     = (float*)allocB((size_t)MBN * 64 * 4);
    float* lin    = (float*)allocB((size_t)MBN * 64 * 4);
    float* sqv    = (float*)allocB((size_t)MBN * 4);
    float* pooled = (float*)allocB((size_t)B * 1024 * 4);
    float* f4     = (float*)allocB((size_t)B * 1024 * 4);
    float* f5     = (float*)allocB((size_t)B * 512 * 4);
    float* skpart = (float*)allocB((size_t)4 * 32 * 1024 * 4);
    short* msh    = (short*)allocB((size_t)MBN * 64 * 2);
    short* msl    = (short*)allocB((size_t)MBN * 64 * 2);
    short* w1h    = (short*)allocB((size_t)64 * 128 * 2);
    short* w1l    = (short*)allocB((size_t)64 * 128 * 2);
    short* w2h    = (short*)allocB((size_t)128 * 512 * 2);
    short* w2l    = (short*)allocB((size_t)128 * 512 * 2);
    short* w3h    = (short*)allocB((size_t)512 * 1024 * 2);
    short* w3l    = (short*)allocB((size_t)512 * 1024 * 2);
    size_t bigOff = off;
    short* f1h = (short*)(w + bigOff);
    short* f1l = (short*)(w + bigOff + 1 * (size_t)MBN * 128 * 2);
    short* f2h = (short*)(w + bigOff + 2 * (size_t)MBN * 128 * 2);
    short* f2l = (short*)(w + bigOff + 2 * (size_t)MBN * 128 * 2 + (size_t)MBN * 512 * 2);
    float* distB = (float*)(w + bigOff);
    size_t distBytes = (size_t)N * N * sizeof(float);
    int chunkB = 1;
    if (ws_size > bigOff) {
        size_t cap = (ws_size - bigOff) / distBytes;
        chunkB = (int)(cap < 32 ? cap : 32);
        if (chunkB < 1) chunkB = 1;
    }

    dim3 blk16(16, 16);
    auto grid64  = [](int M, int Nn) { return dim3((unsigned)((Nn + 63) / 64), (unsigned)((M + 63) / 64)); };
    auto gridMf1 = [](int M, int Nn) { return dim3((unsigned)((Nn / 128) * (M / 128))); };

    // ---- weight splits ----
    split_wt_kernel<<<dim3(128 / 64), 64, 0, stream>>>(Wm[0], w1h, w1l, 64, 128);
    split_wt_kernel<<<dim3(512 / 64), 64, 0, stream>>>(Wm[1], w2h, w2l, 128, 512);
    split_wt_kernel<<<dim3(1024 / 64), 64, 0, stream>>>(Wm[2], w3h, w3l, 512, 1024);

    // ---- 3 GCN layers (exact fp32; selection-sensitive) ----
    const float* featsIn = x;
    float* featsOutArr[3] = { fA, fB, nullptr };
    int Cin[3] = { 3, 64, 64 };
    int dils[3] = { 1, 2, 4 };
    for (int L = 0; L < 3; ++L) {
        sq_kernel<<<(MBN + 255) / 256, 256, 0, stream>>>(featsIn, sqv, MBN, Cin[L]);
        gemm_kernel<0><<<grid64(MBN, 64), blk16, 0, stream>>>(
            featsIn, Wg[L], bg[L], nullptr, nullptr, nullptr, nullptr,
            lin, MBN, Cin[L], 64);
        for (int b0 = 0; b0 < B; b0 += chunkB) {
            int cb = (B - b0 < chunkB) ? (B - b0) : chunkB;
            dist128t_kernel<<<dim3(36, 1, (unsigned)cb), 256, 0, stream>>>(
                featsIn, sqv, distB, b0, N, Cin[L]);
            knn_agg_wave_kernel<<<cb * N / 4, 256, 0, stream>>>(
                distB, lin, gg[L], gb[L], gm[L], gv[L],
                featsOutArr[L], ms, msh, msl, b0, N, dils[L], L);
        }
        featsIn = featsOutArr[L];
    }

    // ---- MLP tail: split-bf16 MFMA (pre-split operands, XCD swizzle) ----
    gemm_mfma_kernel<1><<<gridMf1(MBN, 128), 256, 0, stream>>>(
        msh, msl, w1h, w1l, bm[0], ng[0], nb[0], nm[0], nv[0],
        f1h, f1l, nullptr, MBN, 64, 128, N);
    gemm_mfma_kernel<1><<<gridMf1(MBN, 512), 256, 0, stream>>>(
        f1h, f1l, w2h, w2l, bm[1], ng[1], nb[1], nm[1], nv[1],
        f2h, f2l, nullptr, MBN, 128, 512, N);
    hipMemsetAsync(pooled, 0, (size_t)B * 1024 * sizeof(float), stream);
    gemm_mfma_kernel<2><<<gridMf1(MBN, 1024), 256, 0, stream>>>(
        f2h, f2l, w3h, w3l, bm[2], ng[2], nb[2], nm[2], nv[2],
        nullptr, nullptr, pooled, MBN, 512, 1024, N);

    // ---- M=32 tail layers: skinny split-K + reduce ----
    skinny_gemm_kernel<<<dim3(1024 / 32, 4), 256, 0, stream>>>(pooled, Wm[3], skpart, 1024, 1024);
    skinny_reduce_kernel<1><<<(32 * 1024 + 255) / 256, 256, 0, stream>>>(
        skpart, bm[3], ng[3], nb[3], nm[3], nv[3], f4, 32, 1024, 4);
    skinny_gemm_kernel<<<dim3(512 / 32, 4), 256, 0, stream>>>(f4, Wm[4], skpart, 1024, 512);
    skinny_reduce_kernel<1><<<(32 * 512 + 255) / 256, 256, 0, stream>>>(
        skpart, bm[4], ng[4], nb[4], nm[4], nv[4], f5, 32, 512, 4);
    skinny_gemm_kernel<<<dim3(2, 2), 256, 0, stream>>>(f5, W6, skpart, 512, 40);
    skinny_reduce_kernel<0><<<(32 * 40 + 255) / 256, 256, 0, stream>>>(
        skpart, b6, nullptr, nullptr, nullptr, nullptr, (float*)d_out, 32, 40, 2);
}

// Round 11
// 681.577 us; speedup vs baseline: 1.0375x; 1.0116x over previous
//
#include <hip/hip_runtime.h>
#include <stdint.h>

#define KNN_K 20
#define EPSBN 1e-5f

typedef __attribute__((ext_vector_type(4))) float f32x4;
typedef __attribute__((ext_vector_type(8))) short s16x8;
typedef __attribute__((ext_vector_type(4))) short s16x4;

__device__ __forceinline__ unsigned sortable_f32(float f) {
    unsigned u = __float_as_uint(f);
    return (u & 0x80000000u) ? ~u : (u | 0x80000000u);
}

// round-to-nearest-even float -> bf16 bit pattern
__device__ __forceinline__ short f2bf(float x) {
    unsigned u = __float_as_uint(x);
    unsigned r = (u + 0x7fffu + ((u >> 16) & 1u)) >> 16;
    return (short)r;
}
__device__ __forceinline__ float bf2f(short h) {
    return __uint_as_float(((unsigned)(unsigned short)h) << 16);
}

// ---------------- per-point squared norm ----------------
__global__ void sq_kernel(const float* __restrict__ x, float* __restrict__ sq,
                          int total, int C) {
    int i = blockIdx.x * 256 + threadIdx.x;
    if (i >= total) return;
    const float* p = x + (size_t)i * C;
    float s = 0.f;
    for (int c = 0; c < C; ++c) s += p[c] * p[c];
    sq[i] = s;
}

// ---------------- pairwise squared distances, triangular 128x128 tiles ------
// Computes only tiles bi<=bj (36 of 64) and mirror-writes the transpose.
// EXACT: fp32 add/mul are commutative bitwise; k-ascending fmaf chain is
// identical for (n,m) and (m,n).
__global__ __launch_bounds__(256) void dist128t_kernel(
    const float* __restrict__ feats, const float* __restrict__ sq,
    float* __restrict__ dist, int b0, int N, int C)
{
    int lb = blockIdx.z;
    int b = b0 + lb;
    const float* F = feats + (size_t)b * N * C;
    const float* S = sq + (size_t)b * N;
    float* D = dist + (size_t)lb * N * N;
    int t = blockIdx.x, bi = 0;
    while (t >= 8 - bi) { t -= 8 - bi; ++bi; }
    int bj = bi + t;
    int n0 = bi * 128, m0 = bj * 128;

    __shared__ float As[16][132];
    __shared__ float Bs[16][132];
    int tx = threadIdx.x & 15, ty = threadIdx.x >> 4;
    int tid = threadIdx.x;
    float acc[8][8] = {};
    for (int k0 = 0; k0 < C; k0 += 16) {
        #pragma unroll
        for (int it = 0; it < 8; ++it) {
            int idx = tid + it * 256;
            int r = idx >> 4, kk = idx & 15;
            int gk = k0 + kk;
            As[kk][r] = (gk < C) ? F[(size_t)(n0 + r) * C + gk] : 0.f;
            Bs[kk][r] = (gk < C) ? F[(size_t)(m0 + r) * C + gk] : 0.f;
        }
        __syncthreads();
        #pragma unroll
        for (int kk = 0; kk < 16; ++kk) {
            float4 a0 = *reinterpret_cast<const float4*>(&As[kk][ty * 4]);
            float4 a1 = *reinterpret_cast<const float4*>(&As[kk][64 + ty * 4]);
            float4 b0 = *reinterpret_cast<const float4*>(&Bs[kk][tx * 4]);
            float4 b1 = *reinterpret_cast<const float4*>(&Bs[kk][64 + tx * 4]);
            float av[8] = {a0.x, a0.y, a0.z, a0.w, a1.x, a1.y, a1.z, a1.w};
            float bv[8] = {b0.x, b0.y, b0.z, b0.w, b1.x, b1.y, b1.z, b1.w};
            #pragma unroll
            for (int i = 0; i < 8; ++i)
                #pragma unroll
                for (int j = 0; j < 8; ++j)
                    acc[i][j] = fmaf(av[i], bv[j], acc[i][j]);
        }
        __syncthreads();
    }
    #pragma unroll
    for (int i = 0; i < 8; ++i) {
        int n = n0 + ((i < 4) ? ty * 4 + i : 64 + ty * 4 + (i - 4));
        float sn = S[n];
        #pragma unroll
        for (int j = 0; j < 8; ++j) {
            int m = m0 + ((j < 4) ? tx * 4 + j : 64 + tx * 4 + (j - 4));
            D[(size_t)n * N + m] = (sn + S[m]) - 2.0f * acc[i][j];
        }
    }
    if (bi < bj) {
        #pragma unroll
        for (int j = 0; j < 8; ++j) {
            int m = m0 + ((j < 4) ? tx * 4 + j : 64 + tx * 4 + (j - 4));
            float sm = S[m];
            #pragma unroll
            for (int i = 0; i < 8; ++i) {
                int n = n0 + ((i < 4) ? ty * 4 + i : 64 + ty * 4 + (i - 4));
                D[(size_t)m * N + n] = (sm + S[n]) - 2.0f * acc[i][j];
            }
        }
    }
}

// ---------------- wave-per-point KNN select + aggregate + BN + ReLU ---------
// 4 points per 256-thread block, one wave each. No block barriers.
// R11: single-variable change vs R10 — compaction via ballot+popc (no
// serialized same-address LDS atomics). Candidate ORDER changes, but ranks
// are computed by VALUE over a total order => identical selection/output.
// mode: 0 ms=val, 1 ms+=val, 2 final mean -> bf16 hi/lo split (msh/msl)
__global__ __launch_bounds__(256) void knn_agg_wave_kernel(
    const float* __restrict__ dist, const float* __restrict__ lin,
    const float* __restrict__ gam, const float* __restrict__ bet,
    const float* __restrict__ mu, const float* __restrict__ var,
    float* __restrict__ feats_out, float* __restrict__ ms,
    short* __restrict__ msh, short* __restrict__ msl,
    int b0, int N, int dil, int mode)
{
    // per-point LDS: packed u16x2 histogram (2048 bins), candidates, nbrs
    __shared__ alignas(16) unsigned hist[4][1024];
    __shared__ unsigned long long cand[4][256];
    __shared__ int nbrs[4][KNN_K];

    int tid = threadIdx.x;
    int wv = tid >> 6, lane = tid & 63;
    int p = blockIdx.x * 4 + wv;
    int lb = p / N, n = p - lb * N;
    int b = b0 + lb;
    const int R = KNN_K * dil + 1;   // smallest keys needed (incl self)

    // load 16 distances/lane (coalesced float4), build sortable keys in regs
    const float* drow = dist + ((size_t)lb * N + n) * N;
    const f32x4* drow4 = (const f32x4*)drow;
    unsigned long long k[16];
    #pragma unroll
    for (int s = 0; s < 4; ++s) {
        f32x4 v = drow4[s * 64 + lane];
        #pragma unroll
        for (int e = 0; e < 4; ++e) {
            int m = (s * 64 + lane) * 4 + e;
            k[s * 4 + e] = ((unsigned long long)sortable_f32(v[e]) << 32) | (unsigned)m;
        }
    }
    // zero histogram (1024 words / wave)
    unsigned* H = hist[wv];
    {
        uint4 z = {0u, 0u, 0u, 0u};
        #pragma unroll
        for (int i = 0; i < 4; ++i) *(uint4*)&H[lane * 16 + i * 4] = z;
    }
    __threadfence_block();
    // histogram on top 11 bits (bin d -> word d>>1, half d&1)
    #pragma unroll
    for (int s = 0; s < 16; ++s) {
        unsigned d = (unsigned)(k[s] >> 53);
        atomicAdd(&H[d >> 1], 1u << ((d & 1) << 4));
    }
    __threadfence_block();
    // per-lane 32-bin segment count + wave inclusive scan
    unsigned w[16];
    #pragma unroll
    for (int i = 0; i < 4; ++i) *(uint4*)&w[i * 4] = *(const uint4*)&H[lane * 16 + i * 4];
    int psum = 0;
    #pragma unroll
    for (int i = 0; i < 16; ++i) psum += (int)(w[i] & 0xFFFFu) + (int)(w[i] >> 16);
    int incl = psum;
    #pragma unroll
    for (int d = 1; d < 64; d <<= 1) {
        int o = __shfl_up(incl, d, 64);
        if (lane >= d) incl += o;
    }
    int excl = incl - psum;
    // pivot bin within the lane whose segment crosses R
    int svDl = 0, c0l = 0, pl = 0;
    bool found = (excl < R && incl >= R);
    if (found) {
        int cum = excl;
        #pragma unroll
        for (int i = 0; i < 32; ++i) {
            int hv = (i & 1) ? (int)(w[i >> 1] >> 16) : (int)(w[i >> 1] & 0xFFFFu);
            if (cum + hv >= R) { svDl = lane * 32 + i; c0l = cum; pl = hv; break; }
            cum += hv;
        }
    }
    unsigned long long fm = __ballot(found);
    int src = __ffsll(fm) - 1;
    int svD  = __shfl(svDl, src, 64);
    int svC0 = __shfl(c0l, src, 64);
    int svP  = __shfl(pl, src, 64);
    int Cnt = svC0 + svP;            // exact count of keys with digit <= pivot

    if (Cnt <= 256) {
        // ballot compaction: slot = running base + popcount of lower set lanes
        unsigned long long below = (1ull << lane) - 1;
        int base = 0;
        #pragma unroll
        for (int s = 0; s < 16; ++s) {
            bool pr = ((unsigned)(k[s] >> 53) <= (unsigned)svD);
            unsigned long long mset = __ballot(pr);
            if (pr) cand[wv][base + (int)__popcll(mset & below)] = k[s];
            base += (int)__popcll(mset);
        }
        __threadfence_block();
        // owned candidates (up to 4/lane); single-pass 4-way rank
        unsigned long long my[4];
        #pragma unroll
        for (int q = 0; q < 4; ++q) {
            int slot = lane + q * 64;
            my[q] = (slot < Cnt) ? cand[wv][slot] : ~0ull;
        }
        int r0 = 0, r1 = 0, r2 = 0, r3 = 0;
        for (int c = 0; c < Cnt; ++c) {
            unsigned long long v = cand[wv][c];
            r0 += (v < my[0]) ? 1 : 0;
            r1 += (v < my[1]) ? 1 : 0;
            r2 += (v < my[2]) ? 1 : 0;
            r3 += (v < my[3]) ? 1 : 0;
        }
        int rr[4] = {r0, r1, r2, r3};
        #pragma unroll
        for (int q = 0; q < 4; ++q) {
            int slot = lane + q * 64;
            if (slot < Cnt && rr[q] >= 1) {
                int q2 = rr[q] - 1;
                if (q2 % dil == 0) {
                    int j = q2 / dil;
                    if (j < KNN_K) nbrs[wv][j] = (int)(my[q] & 0xFFFFFFFFull);
                }
            }
        }
    } else {
        // exact fallback (pathological ties): R x wave-min extraction from regs
        unsigned cm = 0;
        #pragma unroll
        for (int s = 0; s < 16; ++s)
            if ((unsigned)(k[s] >> 53) <= (unsigned)svD) cm |= (1u << s);
        for (int r = 0; r < R; ++r) {
            unsigned long long lm = ~0ull;
            #pragma unroll
            for (int s = 0; s < 16; ++s)
                if ((cm >> s) & 1u) lm = (k[s] < lm) ? k[s] : lm;
            #pragma unroll
            for (int d = 32; d; d >>= 1) {
                unsigned long long o = __shfl_xor(lm, d, 64);
                lm = (o < lm) ? o : lm;
            }
            bool done = false;
            #pragma unroll
            for (int s = 0; s < 16; ++s) {
                if (!done && ((cm >> s) & 1u) && k[s] == lm) {
                    cm &= ~(1u << s);
                    done = true;
                }
            }
            if (r >= 1 && lane == 0) {
                int q2 = r - 1;
                if (q2 % dil == 0) {
                    int j = q2 / dil;
                    if (j < KNN_K) nbrs[wv][j] = (int)(lm & 0xFFFFFFFFull);
                }
            }
        }
    }
    __threadfence_block();

    // aggregate: lane = channel. Same FP association as previous rounds:
    // acc = self + P0 + P1 + P2 + P3, Pg = sum over j = g, g+4, ...
    {
        const float sc = 1.0f / 21.0f;
        size_t base = ((size_t)b * N + n) * 64;
        float part[4];
        #pragma unroll
        for (int g = 0; g < 4; ++g) {
            float pacc = 0.f;
            for (int j = g; j < KNN_K; j += 4)
                pacc += lin[((size_t)b * N + nbrs[wv][j]) * 64 + lane];
            part[g] = pacc;
        }
        float acc = lin[base + lane] + part[0] + part[1] + part[2] + part[3];
        float v = acc * sc;
        v = (v - mu[lane]) / sqrtf(var[lane] + EPSBN) * gam[lane] + bet[lane];
        v = fmaxf(v, 0.f);
        if (feats_out) feats_out[base + lane] = v;
        if (mode == 0) ms[base + lane] = v;
        else if (mode == 1) ms[base + lane] += v;
        else {
            float m3 = (ms[base + lane] + v) * (1.0f / 3.0f);
            short hh = f2bf(m3);
            msh[base + lane] = hh;
            msl[base + lane] = f2bf(m3 - bf2f(hh));
        }
    }
}

// ---------------- 64x64-tile fp32 GEMM (GCN lin layers) ----------------------
template<int EPI>
__global__ __launch_bounds__(256) void gemm_kernel(
    const float* __restrict__ A, const float* __restrict__ W,
    const float* __restrict__ bias,
    const float* __restrict__ gam, const float* __restrict__ bet,
    const float* __restrict__ mu, const float* __restrict__ var,
    float* __restrict__ C,
    int M, int K, int N)
{
    __shared__ float As[16][68];
    __shared__ float Bs[16][68];
    int tx = threadIdx.x, ty = threadIdx.y;
    int tid = ty * 16 + tx;
    int row0 = blockIdx.y * 64, col0 = blockIdx.x * 64;
    float acc[4][4] = {};
    for (int k0 = 0; k0 < K; k0 += 16) {
        #pragma unroll
        for (int it = 0; it < 4; ++it) {
            int idx = tid + it * 256;
            int r = idx >> 4, kk = idx & 15;
            int gr = row0 + r, gk = k0 + kk;
            As[kk][r] = (gr < M && gk < K) ? A[(size_t)gr * K + gk] : 0.f;
        }
        #pragma unroll
        for (int it = 0; it < 4; ++it) {
            int idx = tid + it * 256;
            int kk = idx >> 6, c = idx & 63;
            int gk = k0 + kk, gc = col0 + c;
            Bs[kk][c] = (gk < K && gc < N) ? W[(size_t)gk * N + gc] : 0.f;
        }
        __syncthreads();
        #pragma unroll
        for (int kk = 0; kk < 16; ++kk) {
            float4 a4 = *reinterpret_cast<const float4*>(&As[kk][ty * 4]);
            float4 b4 = *reinterpret_cast<const float4*>(&Bs[kk][tx * 4]);
            float av[4] = {a4.x, a4.y, a4.z, a4.w};
            float bv[4] = {b4.x, b4.y, b4.z, b4.w};
            #pragma unroll
            for (int i = 0; i < 4; ++i)
                #pragma unroll
                for (int j = 0; j < 4; ++j)
                    acc[i][j] = fmaf(av[i], bv[j], acc[i][j]);
        }
        __syncthreads();
    }
    #pragma unroll
    for (int i = 0; i < 4; ++i) {
        int r = row0 + ty * 4 + i;
        if (r >= M) break;
        #pragma unroll
        for (int j = 0; j < 4; ++j) {
            int c = col0 + tx * 4 + j;
            if (c >= N) continue;
            float val = acc[i][j] + bias[c];
            if (EPI >= 1) {
                val = (val - mu[c]) / sqrtf(var[c] + EPSBN) * gam[c] + bet[c];
                val = fmaxf(val, 0.f);
            }
            C[(size_t)r * N + c] = val;
        }
    }
}

// ---------------- skinny split-K GEMM for M=32 tail layers -------------------
__global__ __launch_bounds__(256) void skinny_gemm_kernel(
    const float* __restrict__ A, const float* __restrict__ W,
    float* __restrict__ part, int K, int N)
{
    __shared__ float Alds[32][260];
    int tid = threadIdx.x;
    int col0 = blockIdx.x * 32;
    int kc = blockIdx.y;
    int k0 = kc * 256;
    #pragma unroll
    for (int it = 0; it < 8; ++it) {
        int idx = tid + it * 256;
        int r = idx >> 6, kq = (idx & 63) * 4;
        f32x4 v = *(const f32x4*)&A[(size_t)r * K + k0 + kq];
        *(f32x4*)&Alds[r][kq] = v;
    }
    __syncthreads();

    int col = col0 + (tid & 31);
    int g = tid >> 5;
    bool colok = col < N;
    const float* Wp = W + (size_t)k0 * N + (colok ? col : 0);
    float acc0 = 0.f, acc1 = 0.f, acc2 = 0.f, acc3 = 0.f;
    #pragma unroll 4
    for (int k = 0; k < 256; ++k) {
        float wv = Wp[(size_t)k * N];
        acc0 = fmaf(Alds[g * 4 + 0][k], wv, acc0);
        acc1 = fmaf(Alds[g * 4 + 1][k], wv, acc1);
        acc2 = fmaf(Alds[g * 4 + 2][k], wv, acc2);
        acc3 = fmaf(Alds[g * 4 + 3][k], wv, acc3);
    }
    if (colok) {
        size_t base = ((size_t)kc * 32 + g * 4) * N + col;
        part[base]         = acc0;
        part[base + N]     = acc1;
        part[base + 2 * N] = acc2;
        part[base + 3 * N] = acc3;
    }
}

template<int EPI>
__global__ void skinny_reduce_kernel(
    const float* __restrict__ part, const float* __restrict__ bias,
    const float* __restrict__ gam, const float* __restrict__ bet,
    const float* __restrict__ mu, const float* __restrict__ var,
    float* __restrict__ C, int M, int N, int kchunks)
{
    int i = blockIdx.x * 256 + threadIdx.x;
    if (i >= M * N) return;
    int c = i % N;
    float s = 0.f;
    for (int kc = 0; kc < kchunks; ++kc) s += part[(size_t)kc * M * N + i];
    float val = s + bias[c];
    if (EPI >= 1) {
        val = (val - mu[c]) / sqrtf(var[c] + EPSBN) * gam[c] + bet[c];
        val = fmaxf(val, 0.f);
    }
    C[i] = val;
}

// ---------------- weight pre-split: W (KxN fp32) -> Bh,Bl ([N][K] bf16) ------
__global__ void split_wt_kernel(const float* __restrict__ W,
                                short* __restrict__ Bh, short* __restrict__ Bl,
                                int K, int N)
{
    int n = blockIdx.x * 64 + threadIdx.x;
    if (n >= N) return;
    for (int k0 = 0; k0 < K; k0 += 8) {
        s16x8 h, l;
        #pragma unroll
        for (int e = 0; e < 8; ++e) {
            float x = W[(size_t)(k0 + e) * N + n];
            short hh = f2bf(x);
            h[e] = hh;
            l[e] = f2bf(x - bf2f(hh));
        }
        *(s16x8*)&Bh[(size_t)n * K + k0] = h;
        *(s16x8*)&Bl[(size_t)n * K + k0] = l;
    }
}

// ---------------- split-bf16 MFMA GEMM, pre-split operands -------------------
// A: hi/lo bf16 [M][K]; B: hi/lo bf16 [N][K] (transposed). 3-term split.
// 1-D grid with XCD-chunked swizzle. Requires (M/128) % 8 == 0.
// EPI: 1 = bias+BN+ReLU -> bf16 hi/lo split store; 2 = bias+BN+ReLU+maxpool
template<int EPI>
__global__ __launch_bounds__(256) void gemm_mfma_kernel(
    const short* __restrict__ Ah, const short* __restrict__ Al,
    const short* __restrict__ Bh, const short* __restrict__ Bl,
    const float* __restrict__ bias,
    const float* __restrict__ gam, const float* __restrict__ bet,
    const float* __restrict__ mu, const float* __restrict__ var,
    short* __restrict__ Chi, short* __restrict__ Clo,
    float* __restrict__ pool,
    int M, int K, int N, int rowsPerBatch)
{
    __shared__ short Alds[128][72];   // [0..31]=hi k, [32..63]=lo k
    __shared__ short Blds[128][72];
    __shared__ int poolS[128];

    int tid = threadIdx.x;
    int wave = tid >> 6, lane = tid & 63;
    int wr = wave >> 1, wc = wave & 1;
    int nx = N >> 7;
    int rowsPerXcd = (M >> 7) >> 3;
    int bid = blockIdx.x;
    int xcd = bid & 7, l = bid >> 3;
    int tileY = xcd * rowsPerXcd + l / nx;
    int tileX = l - (l / nx) * nx;
    int row0 = tileY * 128, col0 = tileX * 128;

    int fr = lane & 15, fq = lane >> 4;
    int kb = fq * 8;

    f32x4 acc[4][4] = {};

    for (int k0 = 0; k0 < K; k0 += 32) {
        #pragma unroll
        for (int it = 0; it < 2; ++it) {
            int idx = tid + it * 256;
            int r = idx >> 2, ch = (idx & 3) * 8;
            size_t go = (size_t)(row0 + r) * K + k0 + ch;
            *(s16x8*)&Alds[r][ch]      = *(const s16x8*)&Ah[go];
            *(s16x8*)&Alds[r][32 + ch] = *(const s16x8*)&Al[go];
        }
        #pragma unroll
        for (int it = 0; it < 2; ++it) {
            int idx = tid + it * 256;
            int c = idx >> 2, ch = (idx & 3) * 8;
            size_t bo = (size_t)(col0 + c) * K + k0 + ch;
            *(s16x8*)&Blds[c][ch]      = *(const s16x8*)&Bh[bo];
            *(s16x8*)&Blds[c][32 + ch] = *(const s16x8*)&Bl[bo];
        }
        __syncthreads();

        s16x8 ah[4], al[4], bhf[4], blf[4];
        #pragma unroll
        for (int i = 0; i < 4; ++i) {
            int r = wr * 64 + i * 16 + fr;
            ah[i] = *(const s16x8*)&Alds[r][kb];
            al[i] = *(const s16x8*)&Alds[r][32 + kb];
        }
        #pragma unroll
        for (int j = 0; j < 4; ++j) {
            int c = wc * 64 + j * 16 + fr;
            bhf[j] = *(const s16x8*)&Blds[c][kb];
            blf[j] = *(const s16x8*)&Blds[c][32 + kb];
        }
        #pragma unroll
        for (int i = 0; i < 4; ++i)
            #pragma unroll
            for (int j = 0; j < 4; ++j) {
                acc[i][j] = __builtin_amdgcn_mfma_f32_16x16x32_bf16(ah[i], bhf[j], acc[i][j], 0, 0, 0);
                acc[i][j] = __builtin_amdgcn_mfma_f32_16x16x32_bf16(ah[i], blf[j], acc[i][j], 0, 0, 0);
                acc[i][j] = __builtin_amdgcn_mfma_f32_16x16x32_bf16(al[i], bhf[j], acc[i][j], 0, 0, 0);
            }
        __syncthreads();
    }

    if (EPI == 1) {
        #pragma unroll
        for (int j = 0; j < 4; ++j) {
            int col = col0 + wc * 64 + j * 16 + fr;
            float bs = bias[col], g = gam[col], be = bet[col], m = mu[col];
            float inv = 1.0f / sqrtf(var[col] + EPSBN);
            #pragma unroll
            for (int i = 0; i < 4; ++i) {
                int rbase = row0 + wr * 64 + i * 16 + fq * 4;
                #pragma unroll
                for (int reg = 0; reg < 4; ++reg) {
                    float val = acc[i][j][reg] + bs;
                    val = (val - m) * inv * g + be;
                    val = fmaxf(val, 0.f);
                    short hh = f2bf(val);
                    size_t o = (size_t)(rbase + reg) * N + col;
                    Chi[o] = hh;
                    Clo[o] = f2bf(val - bf2f(hh));
                }
            }
        }
    } else {
        float cmax[4];
        #pragma unroll
        for (int j = 0; j < 4; ++j) {
            int col = col0 + wc * 64 + j * 16 + fr;
            float bs = bias[col], g = gam[col], be = bet[col], m = mu[col];
            float inv = 1.0f / sqrtf(var[col] + EPSBN);
            float cm = 0.f;
            #pragma unroll
            for (int i = 0; i < 4; ++i)
                #pragma unroll
                for (int reg = 0; reg < 4; ++reg) {
                    float val = acc[i][j][reg] + bs;
                    val = (val - m) * inv * g + be;
                    val = fmaxf(val, 0.f);
                    cm = fmaxf(cm, val);
                }
            cmax[j] = cm;
        }
        #pragma unroll
        for (int j = 0; j < 4; ++j) {
            cmax[j] = fmaxf(cmax[j], __shfl_xor(cmax[j], 16, 64));
            cmax[j] = fmaxf(cmax[j], __shfl_xor(cmax[j], 32, 64));
        }
        if (tid < 128) poolS[tid] = 0;
        __syncthreads();
        if (fq == 0) {
            #pragma unroll
            for (int j = 0; j < 4; ++j)
                atomicMax(&poolS[wc * 64 + j * 16 + fr], __float_as_int(cmax[j]));
        }
        __syncthreads();
        if (tid < 128) {
            int bb = row0 / rowsPerBatch;
            atomicMax((int*)&pool[(size_t)bb * N + col0 + tid], poolS[tid]);
        }
    }
}

extern "C" void kernel_launch(void* const* d_in, const int* in_sizes, int n_in,
                              void* d_out, int out_size, void* d_ws, size_t ws_size,
                              hipStream_t stream)
{
    (void)in_sizes; (void)n_in; (void)out_size;
    const int B = 32, N = 1024, MBN = B * N;
    const float* x = (const float*)d_in[0];

    const float *Wg[3], *bg[3], *gg[3], *gb[3], *gm[3], *gv[3];
    for (int i = 0; i < 3; ++i) {
        int base = 1 + i * 6;
        Wg[i] = (const float*)d_in[base + 0];
        bg[i] = (const float*)d_in[base + 1];
        gg[i] = (const float*)d_in[base + 2];
        gb[i] = (const float*)d_in[base + 3];
        gm[i] = (const float*)d_in[base + 4];
        gv[i] = (const float*)d_in[base + 5];
    }
    const float *Wm[5], *bm[5], *ng[5], *nb[5], *nm[5], *nv[5];
    for (int i = 0; i < 5; ++i) {
        int base = 19 + i * 6;
        Wm[i] = (const float*)d_in[base + 0];
        bm[i] = (const float*)d_in[base + 1];
        ng[i] = (const float*)d_in[base + 2];
        nb[i] = (const float*)d_in[base + 3];
        nm[i] = (const float*)d_in[base + 4];
        nv[i] = (const float*)d_in[base + 5];
    }
    const float* W6 = (const float*)d_in[49];
    const float* b6 = (const float*)d_in[50];

    // ---- workspace layout (256B-aligned; distB aliases f1h/f1l/f2h/f2l) ----
    char* w = (char*)d_ws;
    size_t off = 0;
    auto allocB = [&](size_t bytes) {
        void* p = w + off;
        off += (bytes + 255) & ~(size_t)255;
        return p;
    };
    float* ms     = (float*)allocB((size_t)MBN * 64 * 4);
    float* fA     = (float*)allocB((size_t)MBN * 64 * 4);
    float* fB     = (float*)allocB((size_t)MBN * 64 * 4);
    float* lin    = (float*)allocB((size_t)MBN * 64 * 4);
    float* sqv    = (float*)allocB((size_t)MBN * 4);
    float* pooled = (float*)allocB((size_t)B * 1024 * 4);
    float* f4     = (float*)allocB((size_t)B * 1024 * 4);
    float* f5     = (float*)allocB((size_t)B * 512 * 4);
    float* skpart = (float*)allocB((size_t)4 * 32 * 1024 * 4);
    short* msh    = (short*)allocB((size_t)MBN * 64 * 2);
    short* msl    = (short*)allocB((size_t)MBN * 64 * 2);
    short* w1h    = (short*)allocB((size_t)64 * 128 * 2);
    short* w1l    = (short*)allocB((size_t)64 * 128 * 2);
    short* w2h    = (short*)allocB((size_t)128 * 512 * 2);
    short* w2l    = (short*)allocB((size_t)128 * 512 * 2);
    short* w3h    = (short*)allocB((size_t)512 * 1024 * 2);
    short* w3l    = (short*)allocB((size_t)512 * 1024 * 2);
    size_t bigOff = off;
    short* f1h = (short*)(w + bigOff);
    short* f1l = (short*)(w + bigOff + 1 * (size_t)MBN * 128 * 2);
    short* f2h = (short*)(w + bigOff + 2 * (size_t)MBN * 128 * 2);
    short* f2l = (short*)(w + bigOff + 2 * (size_t)MBN * 128 * 2 + (size_t)MBN * 512 * 2);
    float* distB = (float*)(w + bigOff);
    size_t distBytes = (size_t)N * N * sizeof(float);
    int chunkB = 1;
    if (ws_size > bigOff) {
        size_t cap = (ws_size - bigOff) / distBytes;
        chunkB = (int)(cap < 32 ? cap : 32);
        if (chunkB < 1) chunkB = 1;
    }

    dim3 blk16(16, 16);
    auto grid64  = [](int M, int Nn) { return dim3((unsigned)((Nn + 63) / 64), (unsigned)((M + 63) / 64)); };
    auto gridMf1 = [](int M, int Nn) { return dim3((unsigned)((Nn / 128) * (M / 128))); };

    // ---- weight splits ----
    split_wt_kernel<<<dim3(128 / 64), 64, 0, stream>>>(Wm[0], w1h, w1l, 64, 128);
    split_wt_kernel<<<dim3(512 / 64), 64, 0, stream>>>(Wm[1], w2h, w2l, 128, 512);
    split_wt_kernel<<<dim3(1024 / 64), 64, 0, stream>>>(Wm[2], w3h, w3l, 512, 1024);

    // ---- 3 GCN layers (exact fp32; selection-sensitive) ----
    const float* featsIn = x;
    float* featsOutArr[3] = { fA, fB, nullptr };
    int Cin[3] = { 3, 64, 64 };
    int dils[3] = { 1, 2, 4 };
    for (int L = 0; L < 3; ++L) {
        sq_kernel<<<(MBN + 255) / 256, 256, 0, stream>>>(featsIn, sqv, MBN, Cin[L]);
        gemm_kernel<0><<<grid64(MBN, 64), blk16, 0, stream>>>(
            featsIn, Wg[L], bg[L], nullptr, nullptr, nullptr, nullptr,
            lin, MBN, Cin[L], 64);
        for (int b0 = 0; b0 < B; b0 += chunkB) {
            int cb = (B - b0 < chunkB) ? (B - b0) : chunkB;
            dist128t_kernel<<<dim3(36, 1, (unsigned)cb), 256, 0, stream>>>(
                featsIn, sqv, distB, b0, N, Cin[L]);
            knn_agg_wave_kernel<<<cb * N / 4, 256, 0, stream>>>(
                distB, lin, gg[L], gb[L], gm[L], gv[L],
                featsOutArr[L], ms, msh, msl, b0, N, dils[L], L);
        }
        featsIn = featsOutArr[L];
    }

    // ---- MLP tail: split-bf16 MFMA (pre-split operands, XCD swizzle) ----
    gemm_mfma_kernel<1><<<gridMf1(MBN, 128), 256, 0, stream>>>(
        msh, msl, w1h, w1l, bm[0], ng[0], nb[0], nm[0], nv[0],
        f1h, f1l, nullptr, MBN, 64, 128, N);
    gemm_mfma_kernel<1><<<gridMf1(MBN, 512), 256, 0, stream>>>(
        f1h, f1l, w2h, w2l, bm[1], ng[1], nb[1], nm[1], nv[1],
        f2h, f2l, nullptr, MBN, 128, 512, N);
    hipMemsetAsync(pooled, 0, (size_t)B * 1024 * sizeof(float), stream);
    gemm_mfma_kernel<2><<<gridMf1(MBN, 1024), 256, 0, stream>>>(
        f2h, f2l, w3h, w3l, bm[2], ng[2], nb[2], nm[2], nv[2],
        nullptr, nullptr, pooled, MBN, 512, 1024, N);

    // ---- M=32 tail layers: skinny split-K + reduce ----
    skinny_gemm_kernel<<<dim3(1024 / 32, 4), 256, 0, stream>>>(pooled, Wm[3], skpart, 1024, 1024);
    skinny_reduce_kernel<1><<<(32 * 1024 + 255) / 256, 256, 0, stream>>>(
        skpart, bm[3], ng[3], nb[3], nm[3], nv[3], f4, 32, 1024, 4);
    skinny_gemm_kernel<<<dim3(512 / 32, 4), 256, 0, stream>>>(f4, Wm[4], skpart, 1024, 512);
    skinny_reduce_kernel<1><<<(32 * 512 + 255) / 256, 256, 0, stream>>>(
        skpart, bm[4], ng[4], nb[4], nm[4], nv[4], f5, 32, 512, 4);
    skinny_gemm_kernel<<<dim3(2, 2), 256, 0, stream>>>(f5, W6, skpart, 512, 40);
    skinny_reduce_kernel<0><<<(32 * 40 + 255) / 256, 256, 0, stream>>>(
        skpart, b6, nullptr, nullptr, nullptr, nullptr, (float*)d_out, 32, 40, 2);
}

// Round 12
// 672.910 us; speedup vs baseline: 1.0509x; 1.0129x over previous
//
#include <hip/hip_runtime.h>
#include <stdint.h>

#define KNN_K 20
#define EPSBN 1e-5f

typedef __attribute__((ext_vector_type(4))) float f32x4;
typedef __attribute__((ext_vector_type(8))) short s16x8;
typedef __attribute__((ext_vector_type(4))) short s16x4;

__device__ __forceinline__ unsigned sortable_f32(float f) {
    unsigned u = __float_as_uint(f);
    return (u & 0x80000000u) ? ~u : (u | 0x80000000u);
}

// round-to-nearest-even float -> bf16 bit pattern
__device__ __forceinline__ short f2bf(float x) {
    unsigned u = __float_as_uint(x);
    unsigned r = (u + 0x7fffu + ((u >> 16) & 1u)) >> 16;
    return (short)r;
}
__device__ __forceinline__ float bf2f(short h) {
    return __uint_as_float(((unsigned)(unsigned short)h) << 16);
}

// async global->LDS, 16B per lane, linear dest (base + lane*16)
__device__ __forceinline__ void gload_lds16(const void* g, void* l) {
    __builtin_amdgcn_global_load_lds(
        (const __attribute__((address_space(1))) unsigned int*)g,
        (__attribute__((address_space(3))) unsigned int*)l, 16, 0, 0);
}

// ---------------- per-point squared norm ----------------
__global__ void sq_kernel(const float* __restrict__ x, float* __restrict__ sq,
                          int total, int C) {
    int i = blockIdx.x * 256 + threadIdx.x;
    if (i >= total) return;
    const float* p = x + (size_t)i * C;
    float s = 0.f;
    for (int c = 0; c < C; ++c) s += p[c] * p[c];
    sq[i] = s;
}

// ---------------- pairwise squared distances, triangular 128x128 tiles ------
// Computes only tiles bi<=bj (36 of 64) and mirror-writes the transpose.
// EXACT: fp32 add/mul are commutative bitwise; k-ascending fmaf chain is
// identical for (n,m) and (m,n).
__global__ __launch_bounds__(256) void dist128t_kernel(
    const float* __restrict__ feats, const float* __restrict__ sq,
    float* __restrict__ dist, int b0, int N, int C)
{
    int lb = blockIdx.z;
    int b = b0 + lb;
    const float* F = feats + (size_t)b * N * C;
    const float* S = sq + (size_t)b * N;
    float* D = dist + (size_t)lb * N * N;
    int t = blockIdx.x, bi = 0;
    while (t >= 8 - bi) { t -= 8 - bi; ++bi; }
    int bj = bi + t;
    int n0 = bi * 128, m0 = bj * 128;

    __shared__ float As[16][132];
    __shared__ float Bs[16][132];
    int tx = threadIdx.x & 15, ty = threadIdx.x >> 4;
    int tid = threadIdx.x;
    float acc[8][8] = {};
    for (int k0 = 0; k0 < C; k0 += 16) {
        #pragma unroll
        for (int it = 0; it < 8; ++it) {
            int idx = tid + it * 256;
            int r = idx >> 4, kk = idx & 15;
            int gk = k0 + kk;
            As[kk][r] = (gk < C) ? F[(size_t)(n0 + r) * C + gk] : 0.f;
            Bs[kk][r] = (gk < C) ? F[(size_t)(m0 + r) * C + gk] : 0.f;
        }
        __syncthreads();
        #pragma unroll
        for (int kk = 0; kk < 16; ++kk) {
            float4 a0 = *reinterpret_cast<const float4*>(&As[kk][ty * 4]);
            float4 a1 = *reinterpret_cast<const float4*>(&As[kk][64 + ty * 4]);
            float4 b0 = *reinterpret_cast<const float4*>(&Bs[kk][tx * 4]);
            float4 b1 = *reinterpret_cast<const float4*>(&Bs[kk][64 + tx * 4]);
            float av[8] = {a0.x, a0.y, a0.z, a0.w, a1.x, a1.y, a1.z, a1.w};
            float bv[8] = {b0.x, b0.y, b0.z, b0.w, b1.x, b1.y, b1.z, b1.w};
            #pragma unroll
            for (int i = 0; i < 8; ++i)
                #pragma unroll
                for (int j = 0; j < 8; ++j)
                    acc[i][j] = fmaf(av[i], bv[j], acc[i][j]);
        }
        __syncthreads();
    }
    #pragma unroll
    for (int i = 0; i < 8; ++i) {
        int n = n0 + ((i < 4) ? ty * 4 + i : 64 + ty * 4 + (i - 4));
        float sn = S[n];
        #pragma unroll
        for (int j = 0; j < 8; ++j) {
            int m = m0 + ((j < 4) ? tx * 4 + j : 64 + tx * 4 + (j - 4));
            D[(size_t)n * N + m] = (sn + S[m]) - 2.0f * acc[i][j];
        }
    }
    if (bi < bj) {
        #pragma unroll
        for (int j = 0; j < 8; ++j) {
            int m = m0 + ((j < 4) ? tx * 4 + j : 64 + tx * 4 + (j - 4));
            float sm = S[m];
            #pragma unroll
            for (int i = 0; i < 8; ++i) {
                int n = n0 + ((i < 4) ? ty * 4 + i : 64 + ty * 4 + (i - 4));
                D[(size_t)m * N + n] = (sm + S[n]) - 2.0f * acc[i][j];
            }
        }
    }
}

// ---------------- wave-per-point KNN select + aggregate + BN + ReLU ---------
// 4 points per 256-thread block, one wave each. No block barriers.
// (R11 best: single-level histogram + ballot compaction.)
// mode: 0 ms=val, 1 ms+=val, 2 final mean -> bf16 hi/lo split (msh/msl)
__global__ __launch_bounds__(256) void knn_agg_wave_kernel(
    const float* __restrict__ dist, const float* __restrict__ lin,
    const float* __restrict__ gam, const float* __restrict__ bet,
    const float* __restrict__ mu, const float* __restrict__ var,
    float* __restrict__ feats_out, float* __restrict__ ms,
    short* __restrict__ msh, short* __restrict__ msl,
    int b0, int N, int dil, int mode)
{
    __shared__ alignas(16) unsigned hist[4][1024];
    __shared__ unsigned long long cand[4][256];
    __shared__ int nbrs[4][KNN_K];

    int tid = threadIdx.x;
    int wv = tid >> 6, lane = tid & 63;
    int p = blockIdx.x * 4 + wv;
    int lb = p / N, n = p - lb * N;
    int b = b0 + lb;
    const int R = KNN_K * dil + 1;

    const float* drow = dist + ((size_t)lb * N + n) * N;
    const f32x4* drow4 = (const f32x4*)drow;
    unsigned long long k[16];
    #pragma unroll
    for (int s = 0; s < 4; ++s) {
        f32x4 v = drow4[s * 64 + lane];
        #pragma unroll
        for (int e = 0; e < 4; ++e) {
            int m = (s * 64 + lane) * 4 + e;
            k[s * 4 + e] = ((unsigned long long)sortable_f32(v[e]) << 32) | (unsigned)m;
        }
    }
    unsigned* H = hist[wv];
    {
        uint4 z = {0u, 0u, 0u, 0u};
        #pragma unroll
        for (int i = 0; i < 4; ++i) *(uint4*)&H[lane * 16 + i * 4] = z;
    }
    __threadfence_block();
    #pragma unroll
    for (int s = 0; s < 16; ++s) {
        unsigned d = (unsigned)(k[s] >> 53);
        atomicAdd(&H[d >> 1], 1u << ((d & 1) << 4));
    }
    __threadfence_block();
    unsigned w[16];
    #pragma unroll
    for (int i = 0; i < 4; ++i) *(uint4*)&w[i * 4] = *(const uint4*)&H[lane * 16 + i * 4];
    int psum = 0;
    #pragma unroll
    for (int i = 0; i < 16; ++i) psum += (int)(w[i] & 0xFFFFu) + (int)(w[i] >> 16);
    int incl = psum;
    #pragma unroll
    for (int d = 1; d < 64; d <<= 1) {
        int o = __shfl_up(incl, d, 64);
        if (lane >= d) incl += o;
    }
    int excl = incl - psum;
    int svDl = 0, c0l = 0, pl = 0;
    bool found = (excl < R && incl >= R);
    if (found) {
        int cum = excl;
        #pragma unroll
        for (int i = 0; i < 32; ++i) {
            int hv = (i & 1) ? (int)(w[i >> 1] >> 16) : (int)(w[i >> 1] & 0xFFFFu);
            if (cum + hv >= R) { svDl = lane * 32 + i; c0l = cum; pl = hv; break; }
            cum += hv;
        }
    }
    unsigned long long fm = __ballot(found);
    int src = __ffsll(fm) - 1;
    int svD  = __shfl(svDl, src, 64);
    int svC0 = __shfl(c0l, src, 64);
    int svP  = __shfl(pl, src, 64);
    int Cnt = svC0 + svP;

    if (Cnt <= 256) {
        unsigned long long below = (1ull << lane) - 1;
        int base = 0;
        #pragma unroll
        for (int s = 0; s < 16; ++s) {
            bool pr = ((unsigned)(k[s] >> 53) <= (unsigned)svD);
            unsigned long long mset = __ballot(pr);
            if (pr) cand[wv][base + (int)__popcll(mset & below)] = k[s];
            base += (int)__popcll(mset);
        }
        __threadfence_block();
        unsigned long long my[4];
        #pragma unroll
        for (int q = 0; q < 4; ++q) {
            int slot = lane + q * 64;
            my[q] = (slot < Cnt) ? cand[wv][slot] : ~0ull;
        }
        int r0 = 0, r1 = 0, r2 = 0, r3 = 0;
        for (int c = 0; c < Cnt; ++c) {
            unsigned long long v = cand[wv][c];
            r0 += (v < my[0]) ? 1 : 0;
            r1 += (v < my[1]) ? 1 : 0;
            r2 += (v < my[2]) ? 1 : 0;
            r3 += (v < my[3]) ? 1 : 0;
        }
        int rr[4] = {r0, r1, r2, r3};
        #pragma unroll
        for (int q = 0; q < 4; ++q) {
            int slot = lane + q * 64;
            if (slot < Cnt && rr[q] >= 1) {
                int q2 = rr[q] - 1;
                if (q2 % dil == 0) {
                    int j = q2 / dil;
                    if (j < KNN_K) nbrs[wv][j] = (int)(my[q] & 0xFFFFFFFFull);
                }
            }
        }
    } else {
        unsigned cm = 0;
        #pragma unroll
        for (int s = 0; s < 16; ++s)
            if ((unsigned)(k[s] >> 53) <= (unsigned)svD) cm |= (1u << s);
        for (int r = 0; r < R; ++r) {
            unsigned long long lm = ~0ull;
            #pragma unroll
            for (int s = 0; s < 16; ++s)
                if ((cm >> s) & 1u) lm = (k[s] < lm) ? k[s] : lm;
            #pragma unroll
            for (int d = 32; d; d >>= 1) {
                unsigned long long o = __shfl_xor(lm, d, 64);
                lm = (o < lm) ? o : lm;
            }
            bool done = false;
            #pragma unroll
            for (int s = 0; s < 16; ++s) {
                if (!done && ((cm >> s) & 1u) && k[s] == lm) {
                    cm &= ~(1u << s);
                    done = true;
                }
            }
            if (r >= 1 && lane == 0) {
                int q2 = r - 1;
                if (q2 % dil == 0) {
                    int j = q2 / dil;
                    if (j < KNN_K) nbrs[wv][j] = (int)(lm & 0xFFFFFFFFull);
                }
            }
        }
    }
    __threadfence_block();

    {
        const float sc = 1.0f / 21.0f;
        size_t base = ((size_t)b * N + n) * 64;
        float part[4];
        #pragma unroll
        for (int g = 0; g < 4; ++g) {
            float pacc = 0.f;
            for (int j = g; j < KNN_K; j += 4)
                pacc += lin[((size_t)b * N + nbrs[wv][j]) * 64 + lane];
            part[g] = pacc;
        }
        float acc = lin[base + lane] + part[0] + part[1] + part[2] + part[3];
        float v = acc * sc;
        v = (v - mu[lane]) / sqrtf(var[lane] + EPSBN) * gam[lane] + bet[lane];
        v = fmaxf(v, 0.f);
        if (feats_out) feats_out[base + lane] = v;
        if (mode == 0) ms[base + lane] = v;
        else if (mode == 1) ms[base + lane] += v;
        else {
            float m3 = (ms[base + lane] + v) * (1.0f / 3.0f);
            short hh = f2bf(m3);
            msh[base + lane] = hh;
            msl[base + lane] = f2bf(m3 - bf2f(hh));
        }
    }
}

// ---------------- 64x64-tile fp32 GEMM (GCN lin layers) ----------------------
template<int EPI>
__global__ __launch_bounds__(256) void gemm_kernel(
    const float* __restrict__ A, const float* __restrict__ W,
    const float* __restrict__ bias,
    const float* __restrict__ gam, const float* __restrict__ bet,
    const float* __restrict__ mu, const float* __restrict__ var,
    float* __restrict__ C,
    int M, int K, int N)
{
    __shared__ float As[16][68];
    __shared__ float Bs[16][68];
    int tx = threadIdx.x, ty = threadIdx.y;
    int tid = ty * 16 + tx;
    int row0 = blockIdx.y * 64, col0 = blockIdx.x * 64;
    float acc[4][4] = {};
    for (int k0 = 0; k0 < K; k0 += 16) {
        #pragma unroll
        for (int it = 0; it < 4; ++it) {
            int idx = tid + it * 256;
            int r = idx >> 4, kk = idx & 15;
            int gr = row0 + r, gk = k0 + kk;
            As[kk][r] = (gr < M && gk < K) ? A[(size_t)gr * K + gk] : 0.f;
        }
        #pragma unroll
        for (int it = 0; it < 4; ++it) {
            int idx = tid + it * 256;
            int kk = idx >> 6, c = idx & 63;
            int gk = k0 + kk, gc = col0 + c;
            Bs[kk][c] = (gk < K && gc < N) ? W[(size_t)gk * N + gc] : 0.f;
        }
        __syncthreads();
        #pragma unroll
        for (int kk = 0; kk < 16; ++kk) {
            float4 a4 = *reinterpret_cast<const float4*>(&As[kk][ty * 4]);
            float4 b4 = *reinterpret_cast<const float4*>(&Bs[kk][tx * 4]);
            float av[4] = {a4.x, a4.y, a4.z, a4.w};
            float bv[4] = {b4.x, b4.y, b4.z, b4.w};
            #pragma unroll
            for (int i = 0; i < 4; ++i)
                #pragma unroll
                for (int j = 0; j < 4; ++j)
                    acc[i][j] = fmaf(av[i], bv[j], acc[i][j]);
        }
        __syncthreads();
    }
    #pragma unroll
    for (int i = 0; i < 4; ++i) {
        int r = row0 + ty * 4 + i;
        if (r >= M) break;
        #pragma unroll
        for (int j = 0; j < 4; ++j) {
            int c = col0 + tx * 4 + j;
            if (c >= N) continue;
            float val = acc[i][j] + bias[c];
            if (EPI >= 1) {
                val = (val - mu[c]) / sqrtf(var[c] + EPSBN) * gam[c] + bet[c];
                val = fmaxf(val, 0.f);
            }
            C[(size_t)r * N + c] = val;
        }
    }
}

// ---------------- skinny split-K GEMM for M=32 tail layers -------------------
__global__ __launch_bounds__(256) void skinny_gemm_kernel(
    const float* __restrict__ A, const float* __restrict__ W,
    float* __restrict__ part, int K, int N)
{
    __shared__ float Alds[32][260];
    int tid = threadIdx.x;
    int col0 = blockIdx.x * 32;
    int kc = blockIdx.y;
    int k0 = kc * 256;
    #pragma unroll
    for (int it = 0; it < 8; ++it) {
        int idx = tid + it * 256;
        int r = idx >> 6, kq = (idx & 63) * 4;
        f32x4 v = *(const f32x4*)&A[(size_t)r * K + k0 + kq];
        *(f32x4*)&Alds[r][kq] = v;
    }
    __syncthreads();

    int col = col0 + (tid & 31);
    int g = tid >> 5;
    bool colok = col < N;
    const float* Wp = W + (size_t)k0 * N + (colok ? col : 0);
    float acc0 = 0.f, acc1 = 0.f, acc2 = 0.f, acc3 = 0.f;
    #pragma unroll 4
    for (int k = 0; k < 256; ++k) {
        float wv = Wp[(size_t)k * N];
        acc0 = fmaf(Alds[g * 4 + 0][k], wv, acc0);
        acc1 = fmaf(Alds[g * 4 + 1][k], wv, acc1);
        acc2 = fmaf(Alds[g * 4 + 2][k], wv, acc2);
        acc3 = fmaf(Alds[g * 4 + 3][k], wv, acc3);
    }
    if (colok) {
        size_t base = ((size_t)kc * 32 + g * 4) * N + col;
        part[base]         = acc0;
        part[base + N]     = acc1;
        part[base + 2 * N] = acc2;
        part[base + 3 * N] = acc3;
    }
}

template<int EPI>
__global__ void skinny_reduce_kernel(
    const float* __restrict__ part, const float* __restrict__ bias,
    const float* __restrict__ gam, const float* __restrict__ bet,
    const float* __restrict__ mu, const float* __restrict__ var,
    float* __restrict__ C, int M, int N, int kchunks)
{
    int i = blockIdx.x * 256 + threadIdx.x;
    if (i >= M * N) return;
    int c = i % N;
    float s = 0.f;
    for (int kc = 0; kc < kchunks; ++kc) s += part[(size_t)kc * M * N + i];
    float val = s + bias[c];
    if (EPI >= 1) {
        val = (val - mu[c]) / sqrtf(var[c] + EPSBN) * gam[c] + bet[c];
        val = fmaxf(val, 0.f);
    }
    C[i] = val;
}

// ---------------- weight pre-split: W (KxN fp32) -> Bh,Bl ([N][K] bf16) ------
__global__ void split_wt_kernel(const float* __restrict__ W,
                                short* __restrict__ Bh, short* __restrict__ Bl,
                                int K, int N)
{
    int n = blockIdx.x * 64 + threadIdx.x;
    if (n >= N) return;
    for (int k0 = 0; k0 < K; k0 += 8) {
        s16x8 h, l;
        #pragma unroll
        for (int e = 0; e < 8; ++e) {
            float x = W[(size_t)(k0 + e) * N + n];
            short hh = f2bf(x);
            h[e] = hh;
            l[e] = f2bf(x - bf2f(hh));
        }
        *(s16x8*)&Bh[(size_t)n * K + k0] = h;
        *(s16x8*)&Bl[(size_t)n * K + k0] = l;
    }
}

// ---------------- split-bf16 MFMA GEMM, pre-split operands -------------------
// A: hi/lo bf16 [M][K]; B: hi/lo bf16 [N][K] (transposed). 3-term split.
// R12: staging via global_load_lds (16B/lane) into LINEAR 64-short rows with
// XOR-swizzled chunk mapping: LDS chunk (r,j) holds source chunk j^(r&7)
// (source chunks 0-3 = hi k-chunks, 4-7 = lo k-chunks). Fragment reads apply
// the same XOR -> <=2-way bank aliasing; HW-linear writes are conflict-free.
// Same 2-barrier loop; MFMA inputs bit-identical to R11.
// 1-D grid with XCD-chunked swizzle. Requires (M/128) % 8 == 0, K % 32 == 0.
// EPI: 1 = bias+BN+ReLU -> bf16 hi/lo split store; 2 = bias+BN+ReLU+maxpool
template<int EPI>
__global__ __launch_bounds__(256) void gemm_mfma_kernel(
    const short* __restrict__ Ah, const short* __restrict__ Al,
    const short* __restrict__ Bh, const short* __restrict__ Bl,
    const float* __restrict__ bias,
    const float* __restrict__ gam, const float* __restrict__ bet,
    const float* __restrict__ mu, const float* __restrict__ var,
    short* __restrict__ Chi, short* __restrict__ Clo,
    float* __restrict__ pool,
    int M, int K, int N, int rowsPerBatch)
{
    __shared__ short Alds[128 * 64];   // row r: 8 chunks of 8 shorts (128B)
    __shared__ short Blds[128 * 64];
    __shared__ int poolS[128];

    int tid = threadIdx.x;
    int wave = tid >> 6, lane = tid & 63;
    int wr = wave >> 1, wc = wave & 1;
    int nx = N >> 7;
    int rowsPerXcd = (M >> 7) >> 3;
    int bid = blockIdx.x;
    int xcd = bid & 7, l = bid >> 3;
    int tileY = xcd * rowsPerXcd + l / nx;
    int tileX = l - (l / nx) * nx;
    int row0 = tileY * 128, col0 = tileX * 128;

    int fr = lane & 15, fq = lane >> 4;

    f32x4 acc[4][4] = {};

    for (int k0 = 0; k0 < K; k0 += 32) {
        // stage A and B: 1024 chunks each; 4 waves x 4 calls x 64 lanes.
        // LDS chunk ci=(r<<3)|j gets source chunk j^(r&7) of row r.
        #pragma unroll
        for (int t = 0; t < 4; ++t) {
            int ci = (wave * 4 + t) * 64 + lane;   // 0..1023
            int r = ci >> 3, j = ci & 7;
            int srce = j ^ (r & 7);
            const short* gA = ((srce < 4) ? Ah : Al)
                + (size_t)(row0 + r) * K + k0 + (srce & 3) * 8;
            gload_lds16(gA, &Alds[(wave * 4 + t) * 512]);
            const short* gB = ((srce < 4) ? Bh : Bl)
                + (size_t)(col0 + r) * K + k0 + (srce & 3) * 8;
            gload_lds16(gB, &Blds[(wave * 4 + t) * 512]);
        }
        __syncthreads();   // drains vmcnt (incl. global_load_lds) before use

        s16x8 ah[4], al[4], bhf[4], blf[4];
        #pragma unroll
        for (int i = 0; i < 4; ++i) {
            int r = wr * 64 + i * 16 + fr;
            int sw = r & 7;
            ah[i] = *(const s16x8*)&Alds[r * 64 + ((fq ^ sw) << 3)];
            al[i] = *(const s16x8*)&Alds[r * 64 + (((4 + fq) ^ sw) << 3)];
        }
        #pragma unroll
        for (int j = 0; j < 4; ++j) {
            int c = wc * 64 + j * 16 + fr;
            int sw = c & 7;
            bhf[j] = *(const s16x8*)&Blds[c * 64 + ((fq ^ sw) << 3)];
            blf[j] = *(const s16x8*)&Blds[c * 64 + (((4 + fq) ^ sw) << 3)];
        }
        #pragma unroll
        for (int i = 0; i < 4; ++i)
            #pragma unroll
            for (int j = 0; j < 4; ++j) {
                acc[i][j] = __builtin_amdgcn_mfma_f32_16x16x32_bf16(ah[i], bhf[j], acc[i][j], 0, 0, 0);
                acc[i][j] = __builtin_amdgcn_mfma_f32_16x16x32_bf16(ah[i], blf[j], acc[i][j], 0, 0, 0);
                acc[i][j] = __builtin_amdgcn_mfma_f32_16x16x32_bf16(al[i], bhf[j], acc[i][j], 0, 0, 0);
            }
        __syncthreads();   // all reads done before next step's staging lands
    }

    if (EPI == 1) {
        #pragma unroll
        for (int j = 0; j < 4; ++j) {
            int col = col0 + wc * 64 + j * 16 + fr;
            float bs = bias[col], g = gam[col], be = bet[col], m = mu[col];
            float inv = 1.0f / sqrtf(var[col] + EPSBN);
            #pragma unroll
            for (int i = 0; i < 4; ++i) {
                int rbase = row0 + wr * 64 + i * 16 + fq * 4;
                #pragma unroll
                for (int reg = 0; reg < 4; ++reg) {
                    float val = acc[i][j][reg] + bs;
                    val = (val - m) * inv * g + be;
                    val = fmaxf(val, 0.f);
                    short hh = f2bf(val);
                    size_t o = (size_t)(rbase + reg) * N + col;
                    Chi[o] = hh;
                    Clo[o] = f2bf(val - bf2f(hh));
                }
            }
        }
    } else {
        float cmax[4];
        #pragma unroll
        for (int j = 0; j < 4; ++j) {
            int col = col0 + wc * 64 + j * 16 + fr;
            float bs = bias[col], g = gam[col], be = bet[col], m = mu[col];
            float inv = 1.0f / sqrtf(var[col] + EPSBN);
            float cm = 0.f;
            #pragma unroll
            for (int i = 0; i < 4; ++i)
                #pragma unroll
                for (int reg = 0; reg < 4; ++reg) {
                    float val = acc[i][j][reg] + bs;
                    val = (val - m) * inv * g + be;
                    val = fmaxf(val, 0.f);
                    cm = fmaxf(cm, val);
                }
            cmax[j] = cm;
        }
        #pragma unroll
        for (int j = 0; j < 4; ++j) {
            cmax[j] = fmaxf(cmax[j], __shfl_xor(cmax[j], 16, 64));
            cmax[j] = fmaxf(cmax[j], __shfl_xor(cmax[j], 32, 64));
        }
        if (tid < 128) poolS[tid] = 0;
        __syncthreads();
        if (fq == 0) {
            #pragma unroll
            for (int j = 0; j < 4; ++j)
                atomicMax(&poolS[wc * 64 + j * 16 + fr], __float_as_int(cmax[j]));
        }
        __syncthreads();
        if (tid < 128) {
            int bb = row0 / rowsPerBatch;
            atomicMax((int*)&pool[(size_t)bb * N + col0 + tid], poolS[tid]);
        }
    }
}

extern "C" void kernel_launch(void* const* d_in, const int* in_sizes, int n_in,
                              void* d_out, int out_size, void* d_ws, size_t ws_size,
                              hipStream_t stream)
{
    (void)in_sizes; (void)n_in; (void)out_size;
    const int B = 32, N = 1024, MBN = B * N;
    const float* x = (const float*)d_in[0];

    const float *Wg[3], *bg[3], *gg[3], *gb[3], *gm[3], *gv[3];
    for (int i = 0; i < 3; ++i) {
        int base = 1 + i * 6;
        Wg[i] = (const float*)d_in[base + 0];
        bg[i] = (const float*)d_in[base + 1];
        gg[i] = (const float*)d_in[base + 2];
        gb[i] = (const float*)d_in[base + 3];
        gm[i] = (const float*)d_in[base + 4];
        gv[i] = (const float*)d_in[base + 5];
    }
    const float *Wm[5], *bm[5], *ng[5], *nb[5], *nm[5], *nv[5];
    for (int i = 0; i < 5; ++i) {
        int base = 19 + i * 6;
        Wm[i] = (const float*)d_in[base + 0];
        bm[i] = (const float*)d_in[base + 1];
        ng[i] = (const float*)d_in[base + 2];
        nb[i] = (const float*)d_in[base + 3];
        nm[i] = (const float*)d_in[base + 4];
        nv[i] = (const float*)d_in[base + 5];
    }
    const float* W6 = (const float*)d_in[49];
    const float* b6 = (const float*)d_in[50];

    // ---- workspace layout (256B-aligned; distB aliases f1h/f1l/f2h/f2l) ----
    char* w = (char*)d_ws;
    size_t off = 0;
    auto allocB = [&](size_t bytes) {
        void* p = w + off;
        off += (bytes + 255) & ~(size_t)255;
        return p;
    };
    float* ms     = (float*)allocB((size_t)MBN * 64 * 4);
    float* fA     = (float*)allocB((size_t)MBN * 64 * 4);
    float* fB     = (float*)allocB((size_t)MBN * 64 * 4);
    float* lin    = (float*)allocB((size_t)MBN * 64 * 4);
    float* sqv    = (float*)allocB((size_t)MBN * 4);
    float* pooled = (float*)allocB((size_t)B * 1024 * 4);
    float* f4     = (float*)allocB((size_t)B * 1024 * 4);
    float* f5     = (float*)allocB((size_t)B * 512 * 4);
    float* skpart = (float*)allocB((size_t)4 * 32 * 1024 * 4);
    short* msh    = (short*)allocB((size_t)MBN * 64 * 2);
    short* msl    = (short*)allocB((size_t)MBN * 64 * 2);
    short* w1h    = (short*)allocB((size_t)64 * 128 * 2);
    short* w1l    = (short*)allocB((size_t)64 * 128 * 2);
    short* w2h    = (short*)allocB((size_t)128 * 512 * 2);
    short* w2l    = (short*)allocB((size_t)128 * 512 * 2);
    short* w3h    = (short*)allocB((size_t)512 * 1024 * 2);
    short* w3l    = (short*)allocB((size_t)512 * 1024 * 2);
    size_t bigOff = off;
    short* f1h = (short*)(w + bigOff);
    short* f1l = (short*)(w + bigOff + 1 * (size_t)MBN * 128 * 2);
    short* f2h = (short*)(w + bigOff + 2 * (size_t)MBN * 128 * 2);
    short* f2l = (short*)(w + bigOff + 2 * (size_t)MBN * 128 * 2 + (size_t)MBN * 512 * 2);
    float* distB = (float*)(w + bigOff);
    size_t distBytes = (size_t)N * N * sizeof(float);
    int chunkB = 1;
    if (ws_size > bigOff) {
        size_t cap = (ws_size - bigOff) / distBytes;
        chunkB = (int)(cap < 32 ? cap : 32);
        if (chunkB < 1) chunkB = 1;
    }

    dim3 blk16(16, 16);
    auto grid64  = [](int M, int Nn) { return dim3((unsigned)((Nn + 63) / 64), (unsigned)((M + 63) / 64)); };
    auto gridMf1 = [](int M, int Nn) { return dim3((unsigned)((Nn / 128) * (M / 128))); };

    // ---- weight splits ----
    split_wt_kernel<<<dim3(128 / 64), 64, 0, stream>>>(Wm[0], w1h, w1l, 64, 128);
    split_wt_kernel<<<dim3(512 / 64), 64, 0, stream>>>(Wm[1], w2h, w2l, 128, 512);
    split_wt_kernel<<<dim3(1024 / 64), 64, 0, stream>>>(Wm[2], w3h, w3l, 512, 1024);

    // ---- 3 GCN layers (exact fp32; selection-sensitive) ----
    const float* featsIn = x;
    float* featsOutArr[3] = { fA, fB, nullptr };
    int Cin[3] = { 3, 64, 64 };
    int dils[3] = { 1, 2, 4 };
    for (int L = 0; L < 3; ++L) {
        sq_kernel<<<(MBN + 255) / 256, 256, 0, stream>>>(featsIn, sqv, MBN, Cin[L]);
        gemm_kernel<0><<<grid64(MBN, 64), blk16, 0, stream>>>(
            featsIn, Wg[L], bg[L], nullptr, nullptr, nullptr, nullptr,
            lin, MBN, Cin[L], 64);
        for (int b0 = 0; b0 < B; b0 += chunkB) {
            int cb = (B - b0 < chunkB) ? (B - b0) : chunkB;
            dist128t_kernel<<<dim3(36, 1, (unsigned)cb), 256, 0, stream>>>(
                featsIn, sqv, distB, b0, N, Cin[L]);
            knn_agg_wave_kernel<<<cb * N / 4, 256, 0, stream>>>(
                distB, lin, gg[L], gb[L], gm[L], gv[L],
                featsOutArr[L], ms, msh, msl, b0, N, dils[L], L);
        }
        featsIn = featsOutArr[L];
    }

    // ---- MLP tail: split-bf16 MFMA (gl_lds staging, XCD swizzle) ----
    gemm_mfma_kernel<1><<<gridMf1(MBN, 128), 256, 0, stream>>>(
        msh, msl, w1h, w1l, bm[0], ng[0], nb[0], nm[0], nv[0],
        f1h, f1l, nullptr, MBN, 64, 128, N);
    gemm_mfma_kernel<1><<<gridMf1(MBN, 512), 256, 0, stream>>>(
        f1h, f1l, w2h, w2l, bm[1], ng[1], nb[1], nm[1], nv[1],
        f2h, f2l, nullptr, MBN, 128, 512, N);
    hipMemsetAsync(pooled, 0, (size_t)B * 1024 * sizeof(float), stream);
    gemm_mfma_kernel<2><<<gridMf1(MBN, 1024), 256, 0, stream>>>(
        f2h, f2l, w3h, w3l, bm[2], ng[2], nb[2], nm[2], nv[2],
        nullptr, nullptr, pooled, MBN, 512, 1024, N);

    // ---- M=32 tail layers: skinny split-K + reduce ----
    skinny_gemm_kernel<<<dim3(1024 / 32, 4), 256, 0, stream>>>(pooled, Wm[3], skpart, 1024, 1024);
    skinny_reduce_kernel<1><<<(32 * 1024 + 255) / 256, 256, 0, stream>>>(
        skpart, bm[3], ng[3], nb[3], nm[3], nv[3], f4, 32, 1024, 4);
    skinny_gemm_kernel<<<dim3(512 / 32, 4), 256, 0, stream>>>(f4, Wm[4], skpart, 1024, 512);
    skinny_reduce_kernel<1><<<(32 * 512 + 255) / 256, 256, 0, stream>>>(
        skpart, bm[4], ng[4], nb[4], nm[4], nv[4], f5, 32, 512, 4);
    skinny_gemm_kernel<<<dim3(2, 2), 256, 0, stream>>>(f5, W6, skpart, 512, 40);
    skinny_reduce_kernel<0><<<(32 * 40 + 255) / 256, 256, 0, stream>>>(
        skpart, b6, nullptr, nullptr, nullptr, nullptr, (float*)d_out, 32, 40, 2);
}